// Round 1
// baseline (1289.415 us; speedup 1.0000x reference)
//
#include <hip/hip_runtime.h>

#define DI __device__ __forceinline__

// Problem dims
constexpr int B_ = 4, CIN = 64, CH = 256, HWP = 16384;   // pixels per batch (128*128)
constexpr int TT = B_ * HWP;                              // 65536 tokens
constexpr float EPSF = 1e-5f;

// Workspace layout (float offsets)
constexpr size_t OFF_IPWT   = 0;         // 320*256           = 81920
constexpr size_t OFF_QKVWT  = 81920;     // 256*768           = 196608
constexpr size_t OFF_PROJWT = 278528;    // 256*256           = 65536
constexpr size_t OFF_GATEWT = 344064;    // 256*1024          = 262144
constexpr size_t OFF_MU     = 606208;    // 65536
constexpr size_t OFF_RSTD   = 671744;    // 65536
constexpr size_t OFF_GNSUM  = 737280;    // 128: [gn1 s, gn1 s2, gn2 s, gn2 s2] x32
constexpr size_t OFF_GNFIN  = 737408;    // 128: [gn1 mu, gn1 rstd, gn2 mu, gn2 rstd] x32
constexpr size_t OFF_PTOK   = 737536;    // 65536*256 (reused as u after window kernel)
constexpr size_t OFF_AM     = 17514752;  // 65536*256
// total = 34291968 floats = 137.2 MB

DI float fsig(float x)  { return 1.f / (1.f + __expf(-x)); }
DI float ftanh(float x) { return 2.f / (1.f + __expf(-2.f * x)) - 1.f; }

// ---------------- prep: transpose all weights to [k][o] ----------------
__global__ __launch_bounds__(256) void k_prep(const float* __restrict__ ipw,
    const float* __restrict__ qkvw, const float* __restrict__ projw,
    const float* __restrict__ gatesw, float* __restrict__ ws) {
  int i = blockIdx.x * 256 + threadIdx.x;
  if (i < 81920)  { int c = i / 256,  o = i % 256;  ws[OFF_IPWT  + i] = ipw[o * 320 + c];   return; }
  i -= 81920;
  if (i < 196608) { int c = i / 768,  o = i % 768;  ws[OFF_QKVWT + i] = qkvw[o * 256 + c];  return; }
  i -= 196608;
  if (i < 65536)  { int c = i / 256,  o = i % 256;  ws[OFF_PROJWT+ i] = projw[o * 256 + c]; return; }
  i -= 65536;
  if (i < 262144) { int c = i / 1024, o = i % 1024; ws[OFF_GATEWT+ i] = gatesw[o * 256 + c];return; }
}

// ---------------- in_proj GEMM: p_tok[t][o] = comb[t][:] @ W^T + b ----------------
// M=65536 (pix-major per batch), N=256, K=320. BM=128, BN=128, BK=16, 256 thr, 8x8/thread.
__global__ __launch_bounds__(256) void k_inproj(const float* __restrict__ x,
    const float* __restrict__ hin, const float* __restrict__ wT,
    const float* __restrict__ bias, float* __restrict__ p_tok) {
  __shared__ float As[16][128];
  __shared__ float Bs[16][128];
  const int tid = threadIdx.x;
  const int t0 = blockIdx.x * 128;
  const int b = t0 >> 14, pix0 = t0 & 16383;
  const int o0 = blockIdx.y * 128;
  const int tx = tid & 15, ty = tid >> 4;
  float acc[8][8] = {};
  for (int kt = 0; kt < 20; ++kt) {
    const int c0 = kt * 16;
#pragma unroll
    for (int ld = 0; ld < 2; ++ld) {
      int f4 = tid + ld * 256;            // 0..511
      int r = f4 >> 5;                    // 0..15
      int col = (f4 & 31) << 2;           // 0..124
      int c = c0 + r;
      const float* src = (c < 64) ? (x + (((size_t)(b * 64 + c)) << 14))
                                  : (hin + (((size_t)(b * 256 + (c - 64))) << 14));
      *reinterpret_cast<float4*>(&As[r][col]) =
          *reinterpret_cast<const float4*>(src + pix0 + col);
      *reinterpret_cast<float4*>(&Bs[r][col]) =
          *reinterpret_cast<const float4*>(wT + (size_t)c * 256 + o0 + col);
    }
    __syncthreads();
#pragma unroll
    for (int k = 0; k < 16; ++k) {
      float a[8], w[8];
      *reinterpret_cast<float4*>(a)     = *reinterpret_cast<const float4*>(&As[k][tx * 8]);
      *reinterpret_cast<float4*>(a + 4) = *reinterpret_cast<const float4*>(&As[k][tx * 8 + 4]);
      *reinterpret_cast<float4*>(w)     = *reinterpret_cast<const float4*>(&Bs[k][ty * 8]);
      *reinterpret_cast<float4*>(w + 4) = *reinterpret_cast<const float4*>(&Bs[k][ty * 8 + 4]);
#pragma unroll
      for (int i = 0; i < 8; ++i)
#pragma unroll
        for (int j = 0; j < 8; ++j) acc[i][j] = fmaf(a[i], w[j], acc[i][j]);
    }
    __syncthreads();
  }
  float bv[8];
  *reinterpret_cast<float4*>(bv)     = *reinterpret_cast<const float4*>(bias + o0 + ty * 8);
  *reinterpret_cast<float4*>(bv + 4) = *reinterpret_cast<const float4*>(bias + o0 + ty * 8 + 4);
#pragma unroll
  for (int i = 0; i < 8; ++i) {
    int t = t0 + tx * 8 + i;
    float o[8];
#pragma unroll
    for (int j = 0; j < 8; ++j) o[j] = acc[i][j] + bv[j];
    float4* dst = reinterpret_cast<float4*>(p_tok + (size_t)t * 256 + o0 + ty * 8);
    dst[0] = *reinterpret_cast<float4*>(o);
    dst[1] = *reinterpret_cast<float4*>(o + 4);
  }
}

// ---------------- per-token LayerNorm stats ----------------
__global__ __launch_bounds__(256) void k_lnstats(const float* __restrict__ p_tok,
    float* __restrict__ mu_arr, float* __restrict__ rstd_arr) {
  const int wave = threadIdx.x >> 6, lane = threadIdx.x & 63;
  const int t = blockIdx.x * 4 + wave;
  float4 v = *reinterpret_cast<const float4*>(p_tok + (size_t)t * 256 + lane * 4);
  float s  = v.x + v.y + v.z + v.w;
  float s2 = v.x * v.x + v.y * v.y + v.z * v.z + v.w * v.w;
#pragma unroll
  for (int off = 32; off; off >>= 1) { s += __shfl_down(s, off); s2 += __shfl_down(s2, off); }
  if (lane == 0) {
    float mu = s * (1.f / 256.f);
    float var = s2 * (1.f / 256.f) - mu * mu;
    mu_arr[t] = mu;
    rstd_arr[t] = rsqrtf(var + EPSF);
  }
}

// ---------------- fused: LN apply -> QKV -> attention -> proj -> GN1 partials ----------------
// one block per 4x4 window (4096 blocks), 256 threads
__global__ __launch_bounds__(256) void k_winattn(const float* __restrict__ p_tok,
    const float* __restrict__ mu_arr, const float* __restrict__ rstd_arr,
    const float* __restrict__ ln_g, const float* __restrict__ ln_b,
    const float* __restrict__ qkvwT, const float* __restrict__ qkv_b,
    const float* __restrict__ projwT, const float* __restrict__ proj_b,
    float* __restrict__ am, float* __restrict__ gn_sum) {
  __shared__ float xn[256 * 16];   // [c][n] ; reused as attn-out [c][n]
  __shared__ float qkv[12288];     // [j][h][n][d]
  const int tid = threadIdx.x;
  const int win = blockIdx.x;
  const int b = win >> 10, rem = win & 1023, wh = rem >> 5, wcol = rem & 31;
  const int tbase = (b << 14) + wh * 4 * 128 + wcol * 4;
  // phase 1: LN into LDS
  {
    const float lg = ln_g[tid], lb = ln_b[tid];
#pragma unroll
    for (int n = 0; n < 16; ++n) {
      int t = tbase + (n >> 2) * 128 + (n & 3);
      float v = p_tok[(size_t)t * 256 + tid];
      xn[tid * 16 + n] = (v - mu_arr[t]) * rstd_arr[t] * lg + lb;
    }
  }
  __syncthreads();
  // phase 2: qkv GEMM. thread owns o = tid (q), tid+256 (k), tid+512 (v)
  {
    float a0[16] = {}, a1[16] = {}, a2[16] = {};
#pragma unroll 4
    for (int c = 0; c < 256; ++c) {
      float w0 = qkvwT[(size_t)c * 768 + tid];
      float w1 = qkvwT[(size_t)c * 768 + 256 + tid];
      float w2 = qkvwT[(size_t)c * 768 + 512 + tid];
      float xv[16];
#pragma unroll
      for (int u = 0; u < 4; ++u)
        *reinterpret_cast<float4*>(xv + u * 4) =
            *reinterpret_cast<const float4*>(&xn[c * 16 + u * 4]);
#pragma unroll
      for (int n = 0; n < 16; ++n) {
        a0[n] = fmaf(w0, xv[n], a0[n]);
        a1[n] = fmaf(w1, xv[n], a1[n]);
        a2[n] = fmaf(w2, xv[n], a2[n]);
      }
    }
    const float b0 = qkv_b[tid], b1 = qkv_b[256 + tid], b2 = qkv_b[512 + tid];
    const int hh = tid >> 5, d = tid & 31;
#pragma unroll
    for (int n = 0; n < 16; ++n) {
      qkv[(hh * 16 + n) * 32 + d]        = a0[n] + b0;
      qkv[4096 + (hh * 16 + n) * 32 + d] = a1[n] + b1;
      qkv[8192 + (hh * 16 + n) * 32 + d] = a2[n] + b2;
    }
  }
  __syncthreads();
  // phase 3: attention. threads 0..127 -> (head, q-row)
  float oacc[32] = {};
  if (tid < 128) {
    const int hh = tid >> 4, qi = tid & 15;
    float qv[32];
#pragma unroll
    for (int u = 0; u < 8; ++u)
      *reinterpret_cast<float4*>(qv + u * 4) =
          *reinterpret_cast<const float4*>(&qkv[(hh * 16 + qi) * 32 + u * 4]);
    float sc[16];
#pragma unroll
    for (int j = 0; j < 16; ++j) {
      const float* kr = &qkv[4096 + (hh * 16 + j) * 32];
      float s = 0.f;
#pragma unroll
      for (int u = 0; u < 32; ++u) s = fmaf(qv[u], kr[u], s);
      sc[j] = s * 0.17677669529663687f;   // 1/sqrt(32)
    }
    float m = sc[0];
#pragma unroll
    for (int j = 1; j < 16; ++j) m = fmaxf(m, sc[j]);
    float ssum = 0.f;
#pragma unroll
    for (int j = 0; j < 16; ++j) { sc[j] = __expf(sc[j] - m); ssum += sc[j]; }
    const float inv = 1.f / ssum;
#pragma unroll
    for (int j = 0; j < 16; ++j) {
      const float p = sc[j] * inv;
      const float* vr = &qkv[8192 + (hh * 16 + j) * 32];
#pragma unroll
      for (int u = 0; u < 32; ++u) oacc[u] = fmaf(p, vr[u], oacc[u]);
    }
  }
  __syncthreads();           // xn reads done -> safe to overwrite
  if (tid < 128) {
    const int hh = tid >> 4, qi = tid & 15;
#pragma unroll
    for (int u = 0; u < 32; ++u) xn[(hh * 32 + u) * 16 + qi] = oacc[u];
  }
  __syncthreads();
  // phase 4: proj. thread owns o = tid, accumulates 16 tokens
  {
    float pa[16] = {};
#pragma unroll 4
    for (int c = 0; c < 256; ++c) {
      float w = projwT[(size_t)c * 256 + tid];
      float av[16];
#pragma unroll
      for (int u = 0; u < 4; ++u)
        *reinterpret_cast<float4*>(av + u * 4) =
            *reinterpret_cast<const float4*>(&xn[c * 16 + u * 4]);
#pragma unroll
      for (int n = 0; n < 16; ++n) pa[n] = fmaf(w, av[n], pa[n]);
    }
    const float pb = proj_b[tid];
    float s = 0.f, s2 = 0.f;
#pragma unroll
    for (int n = 0; n < 16; ++n) {
      int t = tbase + (n >> 2) * 128 + (n & 3);
      float o = pa[n] + pb;
      am[(size_t)t * 256 + tid] = o;
      s += o; s2 += o * o;
    }
#pragma unroll
    for (int off = 16; off; off >>= 1) {
      s  += __shfl_down(s, off, 32);
      s2 += __shfl_down(s2, off, 32);
    }
    if ((tid & 31) == 0) {
      const int g = tid >> 5;
      atomicAdd(&gn_sum[b * 8 + g], s);
      atomicAdd(&gn_sum[32 + b * 8 + g], s2);
    }
  }
}

// ---------------- finalize group-norm stats (32 slots) ----------------
__global__ void k_gnfin(const float* __restrict__ sums, float* __restrict__ fin) {
  const int i = threadIdx.x;  // 0..31
  const float invN = 1.f / 524288.f;   // 32 ch * 16384 pix
  float mu = sums[i] * invN;
  float var = sums[32 + i] * invN - mu * mu;
  fin[i] = mu;
  fin[32 + i] = rsqrtf(fmaxf(var, 0.f) + EPSF);
}

// ---------------- normalize am in place (GN1 apply) ----------------
__global__ __launch_bounds__(256) void k_amnorm(float* __restrict__ am,
    const float* __restrict__ fin, const float* __restrict__ gn_g,
    const float* __restrict__ gn_b) {
  const size_t base = ((size_t)blockIdx.x * 256 + threadIdx.x) * 4;
  const int t = (int)(base >> 8);
  const int c = (int)(base & 255);
  const int b = t >> 14, g = c >> 5;
  const float mu = fin[b * 8 + g], rstd = fin[32 + b * 8 + g];
  float4 v = *reinterpret_cast<float4*>(am + base);
  const float4 gg = *reinterpret_cast<const float4*>(gn_g + c);
  const float4 gb = *reinterpret_cast<const float4*>(gn_b + c);
  v.x = (v.x - mu) * rstd * gg.x + gb.x;
  v.y = (v.y - mu) * rstd * gg.y + gb.y;
  v.z = (v.z - mu) * rstd * gg.z + gb.z;
  v.w = (v.w - mu) * rstd * gg.w + gb.w;
  *reinterpret_cast<float4*>(am + base) = v;
}

// ---------------- gates GEMM + LSTM elementwise + GN2 partials ----------------
// BM=128 tokens, 32 ch x 4 gates, BK=16. 256 thr; thread: 8 tok x 2 ch x 4 gates.
__global__ __launch_bounds__(256) void k_gates(const float* __restrict__ am,
    const float* __restrict__ wT, const float* __restrict__ gates_b,
    const float* __restrict__ cin, float* __restrict__ out,
    float* __restrict__ u, float* __restrict__ gn_sum2) {
  __shared__ float As[16][132];
  __shared__ float Bs[16][128];
  __shared__ float red[8];
  const int tid = threadIdx.x;
  const int t0 = blockIdx.x * 128;
  const int b = t0 >> 14, pix0 = t0 & 16383;
  const int ch0 = blockIdx.y * 32;
  const int tx = tid & 15, cy = tid >> 4;
  float acc[4][2][8] = {};   // [gate][ci][tok]
  for (int kt = 0; kt < 16; ++kt) {
    const int c0 = kt * 16;
#pragma unroll
    for (int ld = 0; ld < 2; ++ld) {
      int f4 = tid + ld * 256;          // 0..511
      int tl = f4 >> 2;                 // 0..127
      int c4 = (f4 & 3) << 2;           // 0,4,8,12
      float4 v = *reinterpret_cast<const float4*>(am + (size_t)(t0 + tl) * 256 + c0 + c4);
      As[c4 + 0][tl] = v.x; As[c4 + 1][tl] = v.y; As[c4 + 2][tl] = v.z; As[c4 + 3][tl] = v.w;
      int r = f4 >> 5;                  // 0..15
      int seg = (f4 & 31) >> 3;         // 0..3
      int cl4 = (f4 & 7) << 2;          // 0..28
      *reinterpret_cast<float4*>(&Bs[r][seg * 32 + cl4]) =
          *reinterpret_cast<const float4*>(wT + (size_t)(c0 + r) * 1024 + seg * 256 + ch0 + cl4);
    }
    __syncthreads();
#pragma unroll
    for (int k = 0; k < 16; ++k) {
      float a[8];
      *reinterpret_cast<float4*>(a)     = *reinterpret_cast<const float4*>(&As[k][tx * 8]);
      *reinterpret_cast<float4*>(a + 4) = *reinterpret_cast<const float4*>(&As[k][tx * 8 + 4]);
#pragma unroll
      for (int g = 0; g < 4; ++g) {
        const float w0 = Bs[k][g * 32 + cy * 2];
        const float w1 = Bs[k][g * 32 + cy * 2 + 1];
#pragma unroll
        for (int r = 0; r < 8; ++r) {
          acc[g][0][r] = fmaf(w0, a[r], acc[g][0][r]);
          acc[g][1][r] = fmaf(w1, a[r], acc[g][1][r]);
        }
      }
    }
    __syncthreads();
  }
  // epilogue: LSTM gates
  float ssum = 0.f, ssq = 0.f;
#pragma unroll
  for (int ci = 0; ci < 2; ++ci) {
    const int ch = ch0 + cy * 2 + ci;
    const float bi = gates_b[ch], bf = gates_b[256 + ch];
    const float bo = gates_b[512 + ch], bg = gates_b[768 + ch];
    const size_t base = (((size_t)(b * 256 + ch)) << 14) + pix0 + tx * 8;
    float cv[8];
    *reinterpret_cast<float4*>(cv)     = *reinterpret_cast<const float4*>(cin + base);
    *reinterpret_cast<float4*>(cv + 4) = *reinterpret_cast<const float4*>(cin + base + 4);
    float cn[8], uv[8];
#pragma unroll
    for (int r = 0; r < 8; ++r) {
      const float iv = fsig(acc[0][ci][r] + bi);
      const float fv = fsig(acc[1][ci][r] + bf);
      const float ov = fsig(acc[2][ci][r] + bo);
      const float gv = ftanh(acc[3][ci][r] + bg);
      const float c2 = fv * cv[r] + iv * gv;
      cn[r] = c2;
      const float uu = ov * ftanh(c2);
      uv[r] = uu;
      ssum += uu; ssq += uu * uu;
    }
    float4* cdst = reinterpret_cast<float4*>(out + 16777216 + base);
    cdst[0] = *reinterpret_cast<float4*>(cn);
    cdst[1] = *reinterpret_cast<float4*>(cn + 4);
    float4* udst = reinterpret_cast<float4*>(u + base);
    udst[0] = *reinterpret_cast<float4*>(uv);
    udst[1] = *reinterpret_cast<float4*>(uv + 4);
  }
#pragma unroll
  for (int off = 32; off; off >>= 1) { ssum += __shfl_down(ssum, off); ssq += __shfl_down(ssq, off); }
  const int lane = tid & 63, wv = tid >> 6;
  if (lane == 0) { red[wv] = ssum; red[4 + wv] = ssq; }
  __syncthreads();
  if (tid == 0) {
    float s = red[0] + red[1] + red[2] + red[3];
    float s2 = red[4] + red[5] + red[6] + red[7];
    atomicAdd(&gn_sum2[b * 8 + (ch0 >> 5)], s);
    atomicAdd(&gn_sum2[32 + b * 8 + (ch0 >> 5)], s2);
  }
}

// ---------------- GN2 apply -> hnext ----------------
__global__ __launch_bounds__(256) void k_gnapply(const float* __restrict__ u,
    const float* __restrict__ fin2, const float* __restrict__ gn_g,
    const float* __restrict__ gn_b, float* __restrict__ hout) {
  const size_t base = ((size_t)blockIdx.x * 256 + threadIdx.x) * 4;
  const int b = (int)(base >> 22);
  const int ch = (int)((base >> 14) & 255);
  const int g = ch >> 5;
  const float mu = fin2[b * 8 + g], rstd = fin2[32 + b * 8 + g];
  const float gg = gn_g[ch], gb = gn_b[ch];
  float4 v = *reinterpret_cast<const float4*>(u + base);
  v.x = (v.x - mu) * rstd * gg + gb;
  v.y = (v.y - mu) * rstd * gg + gb;
  v.z = (v.z - mu) * rstd * gg + gb;
  v.w = (v.w - mu) * rstd * gg + gb;
  *reinterpret_cast<float4*>(hout + base) = v;
}

extern "C" void kernel_launch(void* const* d_in, const int* in_sizes, int n_in,
                              void* d_out, int out_size, void* d_ws, size_t ws_size,
                              hipStream_t stream) {
  const float* x      = (const float*)d_in[0];
  const float* h      = (const float*)d_in[1];
  const float* c      = (const float*)d_in[2];
  const float* ipw    = (const float*)d_in[3];
  const float* ipb    = (const float*)d_in[4];
  const float* lng    = (const float*)d_in[5];
  const float* lnb    = (const float*)d_in[6];
  const float* qkvw   = (const float*)d_in[7];
  const float* qkvb   = (const float*)d_in[8];
  const float* projw  = (const float*)d_in[9];
  const float* projb  = (const float*)d_in[10];
  const float* gatesw = (const float*)d_in[11];
  const float* gatesb = (const float*)d_in[12];
  const float* gng    = (const float*)d_in[13];
  const float* gnb    = (const float*)d_in[14];
  float* ws  = (float*)d_ws;
  float* out = (float*)d_out;

  float* ipwT   = ws + OFF_IPWT;
  float* qkvwT  = ws + OFF_QKVWT;
  float* projwT = ws + OFF_PROJWT;
  float* gatewT = ws + OFF_GATEWT;
  float* mu_a   = ws + OFF_MU;
  float* rstd_a = ws + OFF_RSTD;
  float* gnsum  = ws + OFF_GNSUM;
  float* gnfin  = ws + OFF_GNFIN;
  float* p_tok  = ws + OFF_PTOK;   // later reused as u
  float* am     = ws + OFF_AM;

  hipMemsetAsync(gnsum, 0, 128 * sizeof(float), stream);
  k_prep<<<2368, 256, 0, stream>>>(ipw, qkvw, projw, gatesw, ws);
  k_inproj<<<dim3(512, 2), 256, 0, stream>>>(x, h, ipwT, ipb, p_tok);
  k_lnstats<<<16384, 256, 0, stream>>>(p_tok, mu_a, rstd_a);
  k_winattn<<<4096, 256, 0, stream>>>(p_tok, mu_a, rstd_a, lng, lnb, qkvwT, qkvb,
                                      projwT, projb, am, gnsum);
  k_gnfin<<<1, 32, 0, stream>>>(gnsum, gnfin);
  k_amnorm<<<16384, 256, 0, stream>>>(am, gnfin, gng, gnb);
  k_gates<<<dim3(512, 8), 256, 0, stream>>>(am, gatewT, gatesb, c, out,
                                            p_tok /* u */, gnsum + 64);
  k_gnfin<<<1, 32, 0, stream>>>(gnsum + 64, gnfin + 64);
  k_gnapply<<<16384, 256, 0, stream>>>(p_tok /* u */, gnfin + 64, gng, gnb, out);
}

// Round 2
// 821.115 us; speedup vs baseline: 1.5703x; 1.5703x over previous
//
#include <hip/hip_runtime.h>

#define DI __device__ __forceinline__

typedef unsigned short ushort_t;
typedef __attribute__((ext_vector_type(8))) short bf16x8;
typedef __attribute__((ext_vector_type(4))) float f32x4;
typedef __attribute__((ext_vector_type(4))) unsigned short us4;
typedef __attribute__((ext_vector_type(8))) unsigned short us8;

constexpr float EPSF = 1e-5f;

// ---- workspace byte offsets ----
constexpr size_t O_WIP  = 0;                       // 256x320 bf16
constexpr size_t O_WQKV = 163840;                  // 768x256 bf16
constexpr size_t O_WPRJ = 557056;                  // 256x256 bf16
constexpr size_t O_WGAT = 688128;                  // 1024x256 bf16
constexpr size_t O_MU   = 1212416;                 // 65536 f32
constexpr size_t O_RSTD = 1474560;                 // 65536 f32
constexpr size_t O_GN   = 1736704;                 // 128 f32 (gn1 s,s2 | gn2 s,s2)
constexpr size_t O_FIN  = 1737216;                 // 128 f32
constexpr size_t O_R2   = 1740800;                 // 32MB: p / ao / amn
constexpr size_t O_R3   = O_R2 + 33554432;         // 32MB: xn / am
constexpr size_t O_R1   = O_R3 + 33554432;         // 96MB: comb / qkvbuf / u(f32)
// total = O_R1 + 100663296 = 169512960 bytes (~162 MB)

DI ushort_t f2b(float f) {
  unsigned u = __float_as_uint(f);
  u += 0x7fff + ((u >> 16) & 1);          // round-nearest-even
  return (ushort_t)(u >> 16);
}
DI float b2f(ushort_t s) { return __uint_as_float(((unsigned)s) << 16); }

DI void cp16(ushort_t* lds, const ushort_t* g) {
  __builtin_amdgcn_global_load_lds(
      (const __attribute__((address_space(1))) unsigned*)g,
      (__attribute__((address_space(3))) unsigned*)lds, 16, 0, 0);
}

// ---------------- weight convert (layout preserved [o][k]) ----------------
__global__ __launch_bounds__(256) void k_prep(const float* __restrict__ ipw,
    const float* __restrict__ qkvw, const float* __restrict__ projw,
    const float* __restrict__ gatesw, ushort_t* __restrict__ d0,
    ushort_t* __restrict__ d1, ushort_t* __restrict__ d2, ushort_t* __restrict__ d3) {
  int i = blockIdx.x * 256 + threadIdx.x;
  if (i < 81920)  { d0[i] = f2b(ipw[i]);    return; }
  i -= 81920;
  if (i < 196608) { d1[i] = f2b(qkvw[i]);   return; }
  i -= 196608;
  if (i < 65536)  { d2[i] = f2b(projw[i]);  return; }
  i -= 65536;
  if (i < 262144) { d3[i] = f2b(gatesw[i]); return; }
}

// ---------------- transpose x,h (channel-major) -> comb bf16 [t][320] ----------------
__global__ __launch_bounds__(256) void k_comb(const float* __restrict__ x,
    const float* __restrict__ h, ushort_t* __restrict__ comb) {
  __shared__ float tile[32][257];
  const int tid = threadIdx.x;
  const int wid = blockIdx.x;
  const int b = wid / 640, r = wid % 640, ct = r / 64, pt = r % 64;
  const int p0 = pt * 256;
#pragma unroll 8
  for (int i = 0; i < 32; ++i) {
    const int cg = ct * 32 + i;
    const float* src = (cg < 64) ? x + (((size_t)(b * 64 + cg)) << 14)
                                 : h + (((size_t)(b * 256 + (cg - 64))) << 14);
    tile[i][tid] = src[p0 + tid];
  }
  __syncthreads();
  const int c = tid & 31;
#pragma unroll 8
  for (int i2 = 0; i2 < 32; ++i2) {
    const int tl = (tid >> 5) + i2 * 8;
    comb[(size_t)((b << 14) + p0 + tl) * 320 + ct * 32 + c] = f2b(tile[c][tl]);
  }
}

// ---------------- MFMA GEMM core: BM=128 BN=128 BK=32, 256thr, dbuf LDS ----------------
// A [M][K] bf16 row-major, B [N][K] bf16 row-major (weights), acc[4][4] f32x4
template<int K, int KT, bool GATESB>
DI void gemm_main(const ushort_t* __restrict__ A, const ushort_t* __restrict__ B,
                  int t0, int nb, ushort_t* smem, f32x4 acc[4][4]) {
  const int tid = threadIdx.x;
  const int lane = tid & 63, wave = tid >> 6;
  const int w2 = wave * 2;
  const int wm = wave >> 1, wn = wave & 1;
  const int kfs = lane >> 4, cc = lane & 15;
  const int aoff = kfs * 1024 + (wm * 64 + cc) * 8;
  const int boff = 4096 + kfs * 1024 + (wn * 64 + cc) * 8;

  auto stage = [&](int buf, int k0) {
#pragma unroll
    for (int i = 0; i < 2; ++i) {
      const int w2i = w2 + i;
      const int kslot = w2i >> 1;
      const int mrow = ((w2i & 1) << 6) + lane;
      // A tile
      const ushort_t* ga = A + (size_t)(t0 + mrow) * K + k0 + kslot * 8;
      cp16(smem + buf * 8192 + w2i * 512, ga);
      // B tile (optionally gate-remapped rows)
      int ng;
      if (GATESB) ng = ((mrow >> 5) << 8) + nb + (mrow & 31);
      else        ng = nb + mrow;
      const ushort_t* gb = B + (size_t)ng * K + k0 + kslot * 8;
      cp16(smem + buf * 8192 + 4096 + w2i * 512, gb);
    }
  };

  stage(0, 0);
  __syncthreads();
  for (int kt = 0; kt < KT; ++kt) {
    const int cur = (kt & 1) * 8192;
    if (kt + 1 < KT) stage((kt & 1) ^ 1, (kt + 1) * 32);
    bf16x8 a0 = *(const bf16x8*)(smem + cur + aoff);
    bf16x8 a1 = *(const bf16x8*)(smem + cur + aoff + 128);
    bf16x8 a2 = *(const bf16x8*)(smem + cur + aoff + 256);
    bf16x8 a3 = *(const bf16x8*)(smem + cur + aoff + 384);
    bf16x8 b0 = *(const bf16x8*)(smem + cur + boff);
    bf16x8 b1 = *(const bf16x8*)(smem + cur + boff + 128);
    bf16x8 b2 = *(const bf16x8*)(smem + cur + boff + 256);
    bf16x8 b3 = *(const bf16x8*)(smem + cur + boff + 384);
    acc[0][0] = __builtin_amdgcn_mfma_f32_16x16x32_bf16(a0, b0, acc[0][0], 0, 0, 0);
    acc[0][1] = __builtin_amdgcn_mfma_f32_16x16x32_bf16(a0, b1, acc[0][1], 0, 0, 0);
    acc[0][2] = __builtin_amdgcn_mfma_f32_16x16x32_bf16(a0, b2, acc[0][2], 0, 0, 0);
    acc[0][3] = __builtin_amdgcn_mfma_f32_16x16x32_bf16(a0, b3, acc[0][3], 0, 0, 0);
    acc[1][0] = __builtin_amdgcn_mfma_f32_16x16x32_bf16(a1, b0, acc[1][0], 0, 0, 0);
    acc[1][1] = __builtin_amdgcn_mfma_f32_16x16x32_bf16(a1, b1, acc[1][1], 0, 0, 0);
    acc[1][2] = __builtin_amdgcn_mfma_f32_16x16x32_bf16(a1, b2, acc[1][2], 0, 0, 0);
    acc[1][3] = __builtin_amdgcn_mfma_f32_16x16x32_bf16(a1, b3, acc[1][3], 0, 0, 0);
    acc[2][0] = __builtin_amdgcn_mfma_f32_16x16x32_bf16(a2, b0, acc[2][0], 0, 0, 0);
    acc[2][1] = __builtin_amdgcn_mfma_f32_16x16x32_bf16(a2, b1, acc[2][1], 0, 0, 0);
    acc[2][2] = __builtin_amdgcn_mfma_f32_16x16x32_bf16(a2, b2, acc[2][2], 0, 0, 0);
    acc[2][3] = __builtin_amdgcn_mfma_f32_16x16x32_bf16(a2, b3, acc[2][3], 0, 0, 0);
    acc[3][0] = __builtin_amdgcn_mfma_f32_16x16x32_bf16(a3, b0, acc[3][0], 0, 0, 0);
    acc[3][1] = __builtin_amdgcn_mfma_f32_16x16x32_bf16(a3, b1, acc[3][1], 0, 0, 0);
    acc[3][2] = __builtin_amdgcn_mfma_f32_16x16x32_bf16(a3, b2, acc[3][2], 0, 0, 0);
    acc[3][3] = __builtin_amdgcn_mfma_f32_16x16x32_bf16(a3, b3, acc[3][3], 0, 0, 0);
    __syncthreads();
  }
}

// generic epilogue: bias + bf16 store, C row stride NTOT
template<int NTOT>
DI void epi_store(f32x4 acc[4][4], ushort_t* __restrict__ C, const float* __restrict__ bias,
                  int t0, int n0g) {
  const int tid = threadIdx.x, lane = tid & 63, wave = tid >> 6;
  const int wm = wave >> 1, wn = wave & 1;
  const int r0 = (lane >> 4) * 4, cc = lane & 15;
#pragma unroll
  for (int fn = 0; fn < 4; ++fn) {
    const int n = wn * 64 + fn * 16 + cc;
    const float bv = bias[n0g + n];
#pragma unroll
    for (int fm = 0; fm < 4; ++fm) {
#pragma unroll
      for (int r = 0; r < 4; ++r) {
        const int m = wm * 64 + fm * 16 + r0 + r;
        C[(size_t)(t0 + m) * NTOT + n0g + n] = f2b(acc[fm][fn][r] + bv);
      }
    }
  }
}

__global__ __launch_bounds__(256) void k_inproj(const ushort_t* __restrict__ A,
    const ushort_t* __restrict__ B, const float* __restrict__ bias, ushort_t* __restrict__ C) {
  __shared__ ushort_t smem[16384];
  const int wid = blockIdx.x, g = wid & 7, s = wid >> 3;
  const int mt = g * 64 + s / 2, nt = s % 2;
  f32x4 acc[4][4] = {};
  gemm_main<320, 10, false>(A, B, mt * 128, nt * 128, smem, acc);
  epi_store<256>(acc, C, bias, mt * 128, nt * 128);
}

__global__ __launch_bounds__(256) void k_qkv(const ushort_t* __restrict__ A,
    const ushort_t* __restrict__ B, const float* __restrict__ bias, ushort_t* __restrict__ C) {
  __shared__ ushort_t smem[16384];
  const int wid = blockIdx.x, g = wid & 7, s = wid >> 3;
  const int mt = g * 64 + s / 6, nt = s % 6;
  f32x4 acc[4][4] = {};
  gemm_main<256, 8, false>(A, B, mt * 128, nt * 128, smem, acc);
  epi_store<768>(acc, C, bias, mt * 128, nt * 128);
}

// proj: store + GN1 partial sums
__global__ __launch_bounds__(256) void k_proj(const ushort_t* __restrict__ A,
    const ushort_t* __restrict__ B, const float* __restrict__ bias, ushort_t* __restrict__ C,
    float* __restrict__ gnsum) {
  __shared__ ushort_t smem[16384];
  const int wid = blockIdx.x, g = wid & 7, s = wid >> 3;
  const int mt = g * 64 + s / 2, nt = s % 2;
  const int t0 = mt * 128, n0g = nt * 128;
  f32x4 acc[4][4] = {};
  gemm_main<256, 8, false>(A, B, t0, n0g, smem, acc);
  const int tid = threadIdx.x, lane = tid & 63, wave = tid >> 6;
  const int wm = wave >> 1, wn = wave & 1;
  const int r0 = (lane >> 4) * 4, cc = lane & 15;
  float sA = 0.f, s2A = 0.f, sB = 0.f, s2B = 0.f;
#pragma unroll
  for (int fn = 0; fn < 4; ++fn) {
    const int n = wn * 64 + fn * 16 + cc;
    const float bv = bias[n0g + n];
#pragma unroll
    for (int fm = 0; fm < 4; ++fm) {
#pragma unroll
      for (int r = 0; r < 4; ++r) {
        const int m = wm * 64 + fm * 16 + r0 + r;
        const float v = acc[fm][fn][r] + bv;
        C[(size_t)(t0 + m) * 256 + n0g + n] = f2b(v);
        if (fn < 2) { sA += v; s2A += v * v; } else { sB += v; s2B += v * v; }
      }
    }
  }
#pragma unroll
  for (int o = 32; o; o >>= 1) {
    sA += __shfl_down(sA, o); s2A += __shfl_down(s2A, o);
    sB += __shfl_down(sB, o); s2B += __shfl_down(s2B, o);
  }
  if (lane == 0) {
    const int bch = t0 >> 14;
    const int gb0 = (n0g >> 5) + wn * 2;
    atomicAdd(&gnsum[bch * 8 + gb0], sA);      atomicAdd(&gnsum[32 + bch * 8 + gb0], s2A);
    atomicAdd(&gnsum[bch * 8 + gb0 + 1], sB);  atomicAdd(&gnsum[32 + bch * 8 + gb0 + 1], s2B);
  }
}

// gates: GEMM + LDS transpose + LSTM elementwise + GN2 partials
__global__ __launch_bounds__(256) void k_gates(const ushort_t* __restrict__ A,
    const ushort_t* __restrict__ B, const float* __restrict__ gbias,
    const float* __restrict__ cin, float* __restrict__ cnext, float* __restrict__ u,
    float* __restrict__ gnsum2) {
  __shared__ ushort_t smem[16512];   // 33024B: 32KB staging / 64x129 f32 transpose
  const int wid = blockIdx.x, g = wid & 7, s = wid >> 3;
  const int mt = g * 64 + (s >> 3), nt = s & 7;
  const int t0 = mt * 128, ch0 = nt * 32;
  f32x4 acc[4][4] = {};
  gemm_main<256, 8, true>(A, B, t0, ch0, smem, acc);

  float* cs = (float*)smem;
  const int tid = threadIdx.x, lane = tid & 63, wave = tid >> 6;
  const int wm = wave >> 1, wn = wave & 1;
  const int r0 = (lane >> 4) * 4, cc = lane & 15;
  const int bch = t0 >> 14, pix0 = t0 & 16383;
  const int cl = tid >> 3, tq = tid & 7;
  const int ch = ch0 + cl;
  const float bi = gbias[ch], bf_ = gbias[256 + ch];
  const float bo = gbias[512 + ch], bg = gbias[768 + ch];
  float ssum = 0.f, ssq = 0.f;
#pragma unroll
  for (int mh = 0; mh < 2; ++mh) {
    __syncthreads();
    if (wm == mh) {
#pragma unroll
      for (int fm = 0; fm < 4; ++fm)
#pragma unroll
        for (int fn = 0; fn < 4; ++fn)
#pragma unroll
          for (int r = 0; r < 4; ++r)
            cs[(fm * 16 + r0 + r) * 129 + wn * 64 + fn * 16 + cc] = acc[fm][fn][r];
    }
    __syncthreads();
    const size_t base = (((size_t)(bch * 256 + ch)) << 14) + pix0 + mh * 64 + tq * 8;
    float cv[8], cn[8], uv[8];
    *(float4*)cv       = *(const float4*)(cin + base);
    *(float4*)(cv + 4) = *(const float4*)(cin + base + 4);
#pragma unroll
    for (int i = 0; i < 8; ++i) {
      const int t = tq * 8 + i;
      const float zi = cs[t * 129 + cl] + bi;
      const float zf = cs[t * 129 + 32 + cl] + bf_;
      const float zo = cs[t * 129 + 64 + cl] + bo;
      const float zg = cs[t * 129 + 96 + cl] + bg;
      const float iv = 1.f / (1.f + expf(-zi));
      const float fv = 1.f / (1.f + expf(-zf));
      const float ov = 1.f / (1.f + expf(-zo));
      const float gv = tanhf(zg);
      const float c2 = fv * cv[i] + iv * gv;
      cn[i] = c2;
      const float uu = ov * tanhf(c2);
      uv[i] = uu; ssum += uu; ssq += uu * uu;
    }
    *(float4*)(cnext + base)     = *(float4*)cn;
    *(float4*)(cnext + base + 4) = *(float4*)(cn + 4);
    *(float4*)(u + base)         = *(float4*)uv;
    *(float4*)(u + base + 4)     = *(float4*)(uv + 4);
  }
#pragma unroll
  for (int o = 32; o; o >>= 1) { ssum += __shfl_down(ssum, o); ssq += __shfl_down(ssq, o); }
  if (lane == 0) {
    atomicAdd(&gnsum2[bch * 8 + nt], ssum);
    atomicAdd(&gnsum2[32 + bch * 8 + nt], ssq);
  }
}

// ---------------- LN stats over bf16 p_tok ----------------
__global__ __launch_bounds__(256) void k_lnstats(const ushort_t* __restrict__ p,
    float* __restrict__ mu, float* __restrict__ rstd) {
  const int wave = threadIdx.x >> 6, lane = threadIdx.x & 63;
  const int t = blockIdx.x * 4 + wave;
  us4 v = *(const us4*)(p + (size_t)t * 256 + lane * 4);
  const float a = b2f(v[0]), b = b2f(v[1]), c = b2f(v[2]), d = b2f(v[3]);
  float s = a + b + c + d, s2 = a * a + b * b + c * c + d * d;
#pragma unroll
  for (int o = 32; o; o >>= 1) { s += __shfl_down(s, o); s2 += __shfl_down(s2, o); }
  if (lane == 0) {
    const float m = s * (1.f / 256.f);
    const float var = s2 * (1.f / 256.f) - m * m;
    mu[t] = m;
    rstd[t] = rsqrtf(fmaxf(var, 0.f) + EPSF);
  }
}

// ---------------- LN apply -> xn bf16 ----------------
__global__ __launch_bounds__(256) void k_xn(const ushort_t* __restrict__ p,
    const float* __restrict__ mu, const float* __restrict__ rstd,
    const float* __restrict__ lg, const float* __restrict__ lb, ushort_t* __restrict__ xn) {
  const size_t i = ((size_t)blockIdx.x * 256 + threadIdx.x) * 8;
  const int t = (int)(i >> 8), c = (int)(i & 255);
  const float m = mu[t], r = rstd[t];
  us8 v = *(const us8*)(p + i);
  us8 o;
#pragma unroll
  for (int e = 0; e < 8; ++e)
    o[e] = f2b((b2f(v[e]) - m) * r * lg[c + e] + lb[c + e]);
  *(us8*)(xn + i) = o;
}

// ---------------- attention per 4x4 window ----------------
__global__ __launch_bounds__(128) void k_attn(const ushort_t* __restrict__ qkvb,
    ushort_t* __restrict__ ao) {
  __shared__ float ks[4224], vs[4224];   // [8h][16tok][33]
  const int tid = threadIdx.x;
  const int wid = blockIdx.x;
  const int b = wid >> 10, rem = wid & 1023, wh = rem >> 5, wc = rem & 31;
  const int tbase = (b << 14) + wh * 512 + wc * 4;
#pragma unroll 4
  for (int it = 0; it < 16; ++it) {
    const int i = it * 128 + tid;
    const int j = i >> 7, q = i & 127;
    const int which = q >> 6, hh2 = (q >> 3) & 7, d4 = (q & 7) << 2;
    const int tj = tbase + ((j >> 2) << 7) + (j & 3);
    us4 v = *(const us4*)(qkvb + (size_t)tj * 768 + 256 + which * 256 + hh2 * 32 + d4);
    float* dst = (which ? vs : ks) + (hh2 * 16 + j) * 33 + d4;
    dst[0] = b2f(v[0]); dst[1] = b2f(v[1]); dst[2] = b2f(v[2]); dst[3] = b2f(v[3]);
  }
  const int hh = tid >> 4, qi = tid & 15;
  const int tq = tbase + ((qi >> 2) << 7) + (qi & 3);
  float qv[32];
  {
    const ushort_t* qp = qkvb + (size_t)tq * 768 + hh * 32;
#pragma unroll
    for (int uq = 0; uq < 8; ++uq) {
      us4 v = *(const us4*)(qp + uq * 4);
#pragma unroll
      for (int e = 0; e < 4; ++e) qv[uq * 4 + e] = b2f(v[e]);
    }
  }
  __syncthreads();
  float sc[16];
#pragma unroll
  for (int j = 0; j < 16; ++j) {
    const float* kr = ks + (hh * 16 + j) * 33;
    float s = 0.f;
#pragma unroll
    for (int u2 = 0; u2 < 32; ++u2) s = fmaf(qv[u2], kr[u2], s);
    sc[j] = s * 0.17677669529663687f;
  }
  float m = sc[0];
#pragma unroll
  for (int j = 1; j < 16; ++j) m = fmaxf(m, sc[j]);
  float ssum = 0.f;
#pragma unroll
  for (int j = 0; j < 16; ++j) { sc[j] = __expf(sc[j] - m); ssum += sc[j]; }
  const float inv = 1.f / ssum;
  float oacc[32] = {};
#pragma unroll
  for (int j = 0; j < 16; ++j) {
    const float p = sc[j] * inv;
    const float* vr = vs + (hh * 16 + j) * 33;
#pragma unroll
    for (int u2 = 0; u2 < 32; ++u2) oacc[u2] = fmaf(p, vr[u2], oacc[u2]);
  }
  unsigned* dst = (unsigned*)(ao + (size_t)tq * 256 + hh * 32);
#pragma unroll
  for (int uq = 0; uq < 16; ++uq)
    dst[uq] = (unsigned)f2b(oacc[2 * uq]) | ((unsigned)f2b(oacc[2 * uq + 1]) << 16);
}

// ---------------- GN finalize ----------------
__global__ void k_gnfin(const float* __restrict__ sums, float* __restrict__ fin) {
  const int i = threadIdx.x;   // 0..31
  const float invN = 1.f / 524288.f;
  const float m = sums[i] * invN;
  const float var = sums[32 + i] * invN - m * m;
  fin[i] = m;
  fin[32 + i] = rsqrtf(fmaxf(var, 0.f) + EPSF);
}

// ---------------- GN1 apply: am bf16 -> amn bf16 ----------------
__global__ __launch_bounds__(256) void k_amn(const ushort_t* __restrict__ am,
    const float* __restrict__ fin, const float* __restrict__ gg,
    const float* __restrict__ gb, ushort_t* __restrict__ amn) {
  const size_t i = ((size_t)blockIdx.x * 256 + threadIdx.x) * 8;
  const int t = (int)(i >> 8), c = (int)(i & 255);
  const int b = t >> 14, grp = c >> 5;
  const float m = fin[b * 8 + grp], r = fin[32 + b * 8 + grp];
  us8 v = *(const us8*)(am + i);
  us8 o;
#pragma unroll
  for (int e = 0; e < 8; ++e)
    o[e] = f2b((b2f(v[e]) - m) * r * gg[c + e] + gb[c + e]);
  *(us8*)(amn + i) = o;
}

// ---------------- GN2 apply: u f32 -> hnext f32 ----------------
__global__ __launch_bounds__(256) void k_gnapply(const float* __restrict__ u,
    const float* __restrict__ fin2, const float* __restrict__ gg,
    const float* __restrict__ gb, float* __restrict__ hout) {
  const size_t base = ((size_t)blockIdx.x * 256 + threadIdx.x) * 4;
  const int b = (int)(base >> 22);
  const int ch = (int)((base >> 14) & 255);
  const int grp = ch >> 5;
  const float m = fin2[b * 8 + grp], r = fin2[32 + b * 8 + grp];
  const float gv = gg[ch], bv = gb[ch];
  float4 v = *(const float4*)(u + base);
  v.x = (v.x - m) * r * gv + bv;
  v.y = (v.y - m) * r * gv + bv;
  v.z = (v.z - m) * r * gv + bv;
  v.w = (v.w - m) * r * gv + bv;
  *(float4*)(hout + base) = v;
}

extern "C" void kernel_launch(void* const* d_in, const int* in_sizes, int n_in,
                              void* d_out, int out_size, void* d_ws, size_t ws_size,
                              hipStream_t stream) {
  const float* x      = (const float*)d_in[0];
  const float* h      = (const float*)d_in[1];
  const float* c      = (const float*)d_in[2];
  const float* ipw    = (const float*)d_in[3];
  const float* ipb    = (const float*)d_in[4];
  const float* lng    = (const float*)d_in[5];
  const float* lnb    = (const float*)d_in[6];
  const float* qkvw   = (const float*)d_in[7];
  const float* qkvb   = (const float*)d_in[8];
  const float* projw  = (const float*)d_in[9];
  const float* projb  = (const float*)d_in[10];
  const float* gatesw = (const float*)d_in[11];
  const float* gatesb = (const float*)d_in[12];
  const float* gng    = (const float*)d_in[13];
  const float* gnb    = (const float*)d_in[14];
  char* wsb  = (char*)d_ws;
  float* out = (float*)d_out;

  ushort_t* wip  = (ushort_t*)(wsb + O_WIP);
  ushort_t* wqkv = (ushort_t*)(wsb + O_WQKV);
  ushort_t* wprj = (ushort_t*)(wsb + O_WPRJ);
  ushort_t* wgat = (ushort_t*)(wsb + O_WGAT);
  float* mu_a    = (float*)(wsb + O_MU);
  float* rstd_a  = (float*)(wsb + O_RSTD);
  float* gnsum   = (float*)(wsb + O_GN);
  float* gnfin   = (float*)(wsb + O_FIN);
  ushort_t* R2   = (ushort_t*)(wsb + O_R2);   // p / ao / amn
  ushort_t* R3   = (ushort_t*)(wsb + O_R3);   // xn / am
  ushort_t* R1   = (ushort_t*)(wsb + O_R1);   // comb / qkvbuf ; later u (f32)

  hipMemsetAsync(gnsum, 0, 512, stream);
  k_prep<<<2368, 256, 0, stream>>>(ipw, qkvw, projw, gatesw, wip, wqkv, wprj, wgat);
  k_comb<<<2560, 256, 0, stream>>>(x, h, R1);
  k_inproj<<<1024, 256, 0, stream>>>(R1, wip, ipb, R2);
  k_lnstats<<<16384, 256, 0, stream>>>(R2, mu_a, rstd_a);
  k_xn<<<8192, 256, 0, stream>>>(R2, mu_a, rstd_a, lng, lnb, R3);
  k_qkv<<<3072, 256, 0, stream>>>(R3, wqkv, qkvb, R1);
  k_attn<<<4096, 128, 0, stream>>>(R1, R2);
  k_proj<<<1024, 256, 0, stream>>>(R2, wprj, projb, R3, gnsum);
  k_gnfin<<<1, 32, 0, stream>>>(gnsum, gnfin);
  k_amn<<<8192, 256, 0, stream>>>(R3, gnfin, gng, gnb, R2);
  k_gates<<<4096, 256, 0, stream>>>(R2, wgat, gatesb, c, out + 16777216, (float*)R1,
                                    gnsum + 64);
  k_gnfin<<<1, 32, 0, stream>>>(gnsum + 64, gnfin + 64);
  k_gnapply<<<16384, 256, 0, stream>>>((float*)R1, gnfin + 64, gng, gnb, out);
}

// Round 3
// 789.524 us; speedup vs baseline: 1.6332x; 1.0400x over previous
//
#include <hip/hip_runtime.h>

#define DI __device__ __forceinline__

typedef unsigned short ushort_t;
typedef __attribute__((ext_vector_type(8))) short bf16x8;
typedef __attribute__((ext_vector_type(4))) float f32x4;
typedef __attribute__((ext_vector_type(4))) unsigned short us4;
typedef __attribute__((ext_vector_type(8))) unsigned short us8;

constexpr float EPSF = 1e-5f;

// ---- workspace byte offsets ----
constexpr size_t O_WIP  = 0;                       // 256x320 bf16
constexpr size_t O_WQKV = 163840;                  // 768x256 bf16
constexpr size_t O_WPRJ = 557056;                  // 256x256 bf16
constexpr size_t O_WGAT = 688128;                  // 1024x256 bf16
constexpr size_t O_GN   = 1736704;                 // 128 f32 (gn1 s,s2 | gn2 s,s2)
constexpr size_t O_FIN  = 1737216;                 // 128 f32
constexpr size_t O_R2   = 1740800;                 // 32MB: ao / amn
constexpr size_t O_R3   = O_R2 + 33554432;         // 32MB: xn / am
constexpr size_t O_R1   = O_R3 + 33554432;         // 96MB: comb / qkvbuf / u(f32)

DI ushort_t f2b(float f) {
  unsigned u = __float_as_uint(f);
  u += 0x7fff + ((u >> 16) & 1);          // round-nearest-even
  return (ushort_t)(u >> 16);
}
DI float b2f(ushort_t s) { return __uint_as_float(((unsigned)s) << 16); }

DI float fsig(float x) { return 1.f / (1.f + __expf(-x)); }
DI float ftanh(float x) {
  const float e = __expf(-2.f * fabsf(x));
  const float t = (1.f - e) / (1.f + e);
  return copysignf(t, x);
}

DI void cp16(ushort_t* lds, const ushort_t* g) {
  __builtin_amdgcn_global_load_lds(
      (const __attribute__((address_space(1))) unsigned*)g,
      (__attribute__((address_space(3))) unsigned*)lds, 16, 0, 0);
}

// ---------------- weight convert (layout preserved [o][k]) ----------------
__global__ __launch_bounds__(256) void k_prep(const float* __restrict__ ipw,
    const float* __restrict__ qkvw, const float* __restrict__ projw,
    const float* __restrict__ gatesw, ushort_t* __restrict__ d0,
    ushort_t* __restrict__ d1, ushort_t* __restrict__ d2, ushort_t* __restrict__ d3) {
  int i = blockIdx.x * 256 + threadIdx.x;
  if (i < 81920)  { d0[i] = f2b(ipw[i]);    return; }
  i -= 81920;
  if (i < 196608) { d1[i] = f2b(qkvw[i]);   return; }
  i -= 196608;
  if (i < 65536)  { d2[i] = f2b(projw[i]);  return; }
  i -= 65536;
  if (i < 262144) { d3[i] = f2b(gatesw[i]); return; }
}

// ---------------- transpose x,h (channel-major) -> comb bf16 [t][320] ----------------
__global__ __launch_bounds__(256) void k_comb(const float* __restrict__ x,
    const float* __restrict__ h, ushort_t* __restrict__ comb) {
  __shared__ float tile[32][257];
  const int tid = threadIdx.x;
  const int wid = blockIdx.x;
  const int b = wid / 640, r = wid % 640, ct = r / 64, pt = r % 64;
  const int p0 = pt * 256;
#pragma unroll 8
  for (int i = 0; i < 32; ++i) {
    const int cg = ct * 32 + i;
    const float* src = (cg < 64) ? x + (((size_t)(b * 64 + cg)) << 14)
                                 : h + (((size_t)(b * 256 + (cg - 64))) << 14);
    tile[i][tid] = src[p0 + tid];
  }
  __syncthreads();
  const int c = tid & 31;
#pragma unroll 8
  for (int i2 = 0; i2 < 32; ++i2) {
    const int tl = (tid >> 5) + i2 * 8;
    comb[(size_t)((b << 14) + p0 + tl) * 320 + ct * 32 + c] = f2b(tile[c][tl]);
  }
}

// ---------------- MFMA GEMM core: BM=128 BN=128 BK=32, 256thr, dbuf LDS ----------------
template<int K, int KT, bool GATESB>
DI void gemm_main(const ushort_t* __restrict__ A, const ushort_t* __restrict__ B,
                  int t0, int nb, ushort_t* smem, f32x4 acc[4][4]) {
  const int tid = threadIdx.x;
  const int lane = tid & 63, wave = tid >> 6;
  const int w2 = wave * 2;
  const int wm = wave >> 1, wn = wave & 1;
  const int kfs = lane >> 4, cc = lane & 15;
  const int aoff = kfs * 1024 + (wm * 64 + cc) * 8;
  const int boff = 4096 + kfs * 1024 + (wn * 64 + cc) * 8;

  auto stage = [&](int buf, int k0) {
#pragma unroll
    for (int i = 0; i < 2; ++i) {
      const int w2i = w2 + i;
      const int kslot = w2i >> 1;
      const int mrow = ((w2i & 1) << 6) + lane;
      const ushort_t* ga = A + (size_t)(t0 + mrow) * K + k0 + kslot * 8;
      cp16(smem + buf * 8192 + w2i * 512, ga);
      int ng;
      if (GATESB) ng = ((mrow >> 4) & 3) * 256 + nb + ((mrow >> 6) << 4) + (mrow & 15);
      else        ng = nb + mrow;
      const ushort_t* gb = B + (size_t)ng * K + k0 + kslot * 8;
      cp16(smem + buf * 8192 + 4096 + w2i * 512, gb);
    }
  };

  stage(0, 0);
  __syncthreads();
  for (int kt = 0; kt < KT; ++kt) {
    const int cur = (kt & 1) * 8192;
    if (kt + 1 < KT) stage((kt & 1) ^ 1, (kt + 1) * 32);
    bf16x8 a0 = *(const bf16x8*)(smem + cur + aoff);
    bf16x8 a1 = *(const bf16x8*)(smem + cur + aoff + 128);
    bf16x8 a2 = *(const bf16x8*)(smem + cur + aoff + 256);
    bf16x8 a3 = *(const bf16x8*)(smem + cur + aoff + 384);
    bf16x8 b0 = *(const bf16x8*)(smem + cur + boff);
    bf16x8 b1 = *(const bf16x8*)(smem + cur + boff + 128);
    bf16x8 b2 = *(const bf16x8*)(smem + cur + boff + 256);
    bf16x8 b3 = *(const bf16x8*)(smem + cur + boff + 384);
    acc[0][0] = __builtin_amdgcn_mfma_f32_16x16x32_bf16(a0, b0, acc[0][0], 0, 0, 0);
    acc[0][1] = __builtin_amdgcn_mfma_f32_16x16x32_bf16(a0, b1, acc[0][1], 0, 0, 0);
    acc[0][2] = __builtin_amdgcn_mfma_f32_16x16x32_bf16(a0, b2, acc[0][2], 0, 0, 0);
    acc[0][3] = __builtin_amdgcn_mfma_f32_16x16x32_bf16(a0, b3, acc[0][3], 0, 0, 0);
    acc[1][0] = __builtin_amdgcn_mfma_f32_16x16x32_bf16(a1, b0, acc[1][0], 0, 0, 0);
    acc[1][1] = __builtin_amdgcn_mfma_f32_16x16x32_bf16(a1, b1, acc[1][1], 0, 0, 0);
    acc[1][2] = __builtin_amdgcn_mfma_f32_16x16x32_bf16(a1, b2, acc[1][2], 0, 0, 0);
    acc[1][3] = __builtin_amdgcn_mfma_f32_16x16x32_bf16(a1, b3, acc[1][3], 0, 0, 0);
    acc[2][0] = __builtin_amdgcn_mfma_f32_16x16x32_bf16(a2, b0, acc[2][0], 0, 0, 0);
    acc[2][1] = __builtin_amdgcn_mfma_f32_16x16x32_bf16(a2, b1, acc[2][1], 0, 0, 0);
    acc[2][2] = __builtin_amdgcn_mfma_f32_16x16x32_bf16(a2, b2, acc[2][2], 0, 0, 0);
    acc[2][3] = __builtin_amdgcn_mfma_f32_16x16x32_bf16(a2, b3, acc[2][3], 0, 0, 0);
    acc[3][0] = __builtin_amdgcn_mfma_f32_16x16x32_bf16(a3, b0, acc[3][0], 0, 0, 0);
    acc[3][1] = __builtin_amdgcn_mfma_f32_16x16x32_bf16(a3, b1, acc[3][1], 0, 0, 0);
    acc[3][2] = __builtin_amdgcn_mfma_f32_16x16x32_bf16(a3, b2, acc[3][2], 0, 0, 0);
    acc[3][3] = __builtin_amdgcn_mfma_f32_16x16x32_bf16(a3, b3, acc[3][3], 0, 0, 0);
    __syncthreads();
  }
}

template<int NTOT>
DI void epi_store(f32x4 acc[4][4], ushort_t* __restrict__ C, const float* __restrict__ bias,
                  int t0, int n0g) {
  const int tid = threadIdx.x, lane = tid & 63, wave = tid >> 6;
  const int wm = wave >> 1, wn = wave & 1;
  const int r0 = (lane >> 4) * 4, cc = lane & 15;
#pragma unroll
  for (int fn = 0; fn < 4; ++fn) {
    const int n = wn * 64 + fn * 16 + cc;
    const float bv = bias[n0g + n];
#pragma unroll
    for (int fm = 0; fm < 4; ++fm) {
#pragma unroll
      for (int r = 0; r < 4; ++r) {
        const int m = wm * 64 + fm * 16 + r0 + r;
        C[(size_t)(t0 + m) * NTOT + n0g + n] = f2b(acc[fm][fn][r] + bv);
      }
    }
  }
}

// ---------------- in_proj + LayerNorm fused: BM=64 BN=256 ----------------
__global__ __launch_bounds__(256) void k_inproj_ln(const ushort_t* __restrict__ A,
    const ushort_t* __restrict__ B, const float* __restrict__ bias,
    const float* __restrict__ lg, const float* __restrict__ lb, ushort_t* __restrict__ xn) {
  __shared__ ushort_t smem[20480];   // dbuf 2 x (A 2048 + B 8192) ushorts
  __shared__ float red[4][2][64];
  __shared__ float fin[2][64];
  const int tid = threadIdx.x, lane = tid & 63, wave = tid >> 6;
  const int t0 = blockIdx.x * 64;
  const int kfs = lane >> 4, cc = lane & 15;
  const int r0 = kfs * 4;
  const int aoff = kfs * 512 + cc * 8;
  const int boff = 2048 + kfs * 2048 + (wave * 64 + cc) * 8;

  auto stage = [&](int buf, int k0) {
#pragma unroll
    for (int rr = 0; rr < 5; ++rr) {
      const int r = wave * 5 + rr;
      const int e = r * 64 + lane;
      const ushort_t* src;
      if (r < 4) src = A + (size_t)(t0 + (e & 63)) * 320 + k0 + (e >> 6) * 8;
      else { const int e2 = e - 256; src = B + (size_t)(e2 & 255) * 320 + k0 + (e2 >> 8) * 8; }
      cp16(smem + buf * 10240 + r * 512, src);
    }
  };

  stage(0, 0);
  f32x4 acc[4][4] = {};
  __syncthreads();
  for (int kt = 0; kt < 10; ++kt) {
    const int cur = (kt & 1) * 10240;
    if (kt < 9) stage((kt & 1) ^ 1, (kt + 1) * 32);
    bf16x8 av[4], bv[4];
#pragma unroll
    for (int i = 0; i < 4; ++i) av[i] = *(const bf16x8*)(smem + cur + aoff + i * 128);
#pragma unroll
    for (int j = 0; j < 4; ++j) bv[j] = *(const bf16x8*)(smem + cur + boff + j * 128);
#pragma unroll
    for (int i = 0; i < 4; ++i)
#pragma unroll
      for (int j = 0; j < 4; ++j)
        acc[i][j] = __builtin_amdgcn_mfma_f32_16x16x32_bf16(av[i], bv[j], acc[i][j], 0, 0, 0);
    __syncthreads();
  }
  // bias add
  float bcol[4];
#pragma unroll
  for (int j = 0; j < 4; ++j) bcol[j] = bias[wave * 64 + j * 16 + cc];
#pragma unroll
  for (int i = 0; i < 4; ++i)
#pragma unroll
    for (int j = 0; j < 4; ++j)
#pragma unroll
      for (int r = 0; r < 4; ++r) acc[i][j][r] += bcol[j];
  // per-row partial sums over this wave's 64 cols
#pragma unroll
  for (int i = 0; i < 4; ++i) {
#pragma unroll
    for (int r = 0; r < 4; ++r) {
      float s  = acc[i][0][r] + acc[i][1][r] + acc[i][2][r] + acc[i][3][r];
      float s2 = acc[i][0][r] * acc[i][0][r] + acc[i][1][r] * acc[i][1][r]
               + acc[i][2][r] * acc[i][2][r] + acc[i][3][r] * acc[i][3][r];
#pragma unroll
      for (int m = 1; m < 16; m <<= 1) { s += __shfl_xor(s, m); s2 += __shfl_xor(s2, m); }
      if (cc == 0) { red[wave][0][i * 16 + r0 + r] = s; red[wave][1][i * 16 + r0 + r] = s2; }
    }
  }
  __syncthreads();
  if (tid < 64) {
    const float s  = red[0][0][tid] + red[1][0][tid] + red[2][0][tid] + red[3][0][tid];
    const float s2 = red[0][1][tid] + red[1][1][tid] + red[2][1][tid] + red[3][1][tid];
    const float m = s * (1.f / 256.f);
    const float var = s2 * (1.f / 256.f) - m * m;
    fin[0][tid] = m;
    fin[1][tid] = rsqrtf(fmaxf(var, 0.f) + EPSF);
  }
  __syncthreads();
  float lgv[4], lbv[4];
#pragma unroll
  for (int j = 0; j < 4; ++j) {
    const int n = wave * 64 + j * 16 + cc;
    lgv[j] = lg[n]; lbv[j] = lb[n];
  }
#pragma unroll
  for (int i = 0; i < 4; ++i)
#pragma unroll
    for (int r = 0; r < 4; ++r) {
      const int m = i * 16 + r0 + r;
      const float mu = fin[0][m], rs = fin[1][m];
      ushort_t* dst = xn + (size_t)(t0 + m) * 256 + wave * 64 + cc;
#pragma unroll
      for (int j = 0; j < 4; ++j)
        dst[j * 16] = f2b((acc[i][j][r] - mu) * rs * lgv[j] + lbv[j]);
    }
}

__global__ __launch_bounds__(256) void k_qkv(const ushort_t* __restrict__ A,
    const ushort_t* __restrict__ B, const float* __restrict__ bias, ushort_t* __restrict__ C) {
  __shared__ ushort_t smem[16384];
  const int wid = blockIdx.x, g = wid & 7, s = wid >> 3;
  const int mt = g * 64 + s / 6, nt = s % 6;
  f32x4 acc[4][4] = {};
  gemm_main<256, 8, false>(A, B, mt * 128, nt * 128, smem, acc);
  epi_store<768>(acc, C, bias, mt * 128, nt * 128);
}

// proj: store + GN1 partial sums
__global__ __launch_bounds__(256) void k_proj(const ushort_t* __restrict__ A,
    const ushort_t* __restrict__ B, const float* __restrict__ bias, ushort_t* __restrict__ C,
    float* __restrict__ gnsum) {
  __shared__ ushort_t smem[16384];
  const int wid = blockIdx.x, g = wid & 7, s = wid >> 3;
  const int mt = g * 64 + s / 2, nt = s % 2;
  const int t0 = mt * 128, n0g = nt * 128;
  f32x4 acc[4][4] = {};
  gemm_main<256, 8, false>(A, B, t0, n0g, smem, acc);
  const int tid = threadIdx.x, lane = tid & 63, wave = tid >> 6;
  const int wm = wave >> 1, wn = wave & 1;
  const int r0 = (lane >> 4) * 4, cc = lane & 15;
  float sA = 0.f, s2A = 0.f, sB = 0.f, s2B = 0.f;
#pragma unroll
  for (int fn = 0; fn < 4; ++fn) {
    const int n = wn * 64 + fn * 16 + cc;
    const float bv = bias[n0g + n];
#pragma unroll
    for (int fm = 0; fm < 4; ++fm) {
#pragma unroll
      for (int r = 0; r < 4; ++r) {
        const int m = wm * 64 + fm * 16 + r0 + r;
        const float v = acc[fm][fn][r] + bv;
        C[(size_t)(t0 + m) * 256 + n0g + n] = f2b(v);
        if (fn < 2) { sA += v; s2A += v * v; } else { sB += v; s2B += v * v; }
      }
    }
  }
#pragma unroll
  for (int o = 32; o; o >>= 1) {
    sA += __shfl_down(sA, o); s2A += __shfl_down(s2A, o);
    sB += __shfl_down(sB, o); s2B += __shfl_down(s2B, o);
  }
  if (lane == 0) {
    const int bch = t0 >> 14;
    const int gb0 = (n0g >> 5) + wn * 2;
    atomicAdd(&gnsum[bch * 8 + gb0], sA);      atomicAdd(&gnsum[32 + bch * 8 + gb0], s2A);
    atomicAdd(&gnsum[bch * 8 + gb0 + 1], sB);  atomicAdd(&gnsum[32 + bch * 8 + gb0 + 1], s2B);
  }
}

// gates: GEMM + LSTM elementwise in MFMA layout (gate = fn via B-row remap)
__global__ __launch_bounds__(256) void k_gates(const ushort_t* __restrict__ A,
    const ushort_t* __restrict__ B, const float* __restrict__ gbias,
    const float* __restrict__ cin, float* __restrict__ cnext, float* __restrict__ u,
    float* __restrict__ gnsum2) {
  __shared__ ushort_t smem[16384];
  const int wid = blockIdx.x, g = wid & 7, s = wid >> 3;
  const int mt = g * 64 + (s >> 3), nt = s & 7;
  const int t0 = mt * 128, ch0 = nt * 32;
  f32x4 acc[4][4] = {};
  gemm_main<256, 8, true>(A, B, t0, ch0, smem, acc);

  const int tid = threadIdx.x, lane = tid & 63, wave = tid >> 6;
  const int wm = wave >> 1, wn = wave & 1;
  const int r0 = (lane >> 4) * 4, cc = lane & 15;
  const int bch = t0 >> 14, pix0 = t0 & 16383;
  const int ch = ch0 + wn * 16 + cc;
  const float bi = gbias[ch], bf_ = gbias[256 + ch];
  const float bo = gbias[512 + ch], bg = gbias[768 + ch];
  const size_t chbase = ((size_t)(bch * 256 + ch)) << 14;
  float ssum = 0.f, ssq = 0.f;
#pragma unroll
  for (int fm = 0; fm < 4; ++fm) {
    const int pix = pix0 + wm * 64 + fm * 16 + r0;
    const float4 cv = *(const float4*)(cin + chbase + pix);
    float cn[4], uv[4];
#pragma unroll
    for (int r = 0; r < 4; ++r) {
      const float iv = fsig(acc[fm][0][r] + bi);
      const float fv = fsig(acc[fm][1][r] + bf_);
      const float ov = fsig(acc[fm][2][r] + bo);
      const float gv = ftanh(acc[fm][3][r] + bg);
      const float cold = (&cv.x)[r];
      const float c2 = fv * cold + iv * gv;
      cn[r] = c2;
      const float uu = ov * ftanh(c2);
      uv[r] = uu; ssum += uu; ssq += uu * uu;
    }
    *(float4*)(cnext + chbase + pix) = *(float4*)cn;
    *(float4*)(u + chbase + pix)     = *(float4*)uv;
  }
#pragma unroll
  for (int o = 32; o; o >>= 1) { ssum += __shfl_down(ssum, o); ssq += __shfl_down(ssq, o); }
  if (lane == 0) {
    atomicAdd(&gnsum2[bch * 8 + nt], ssum);
    atomicAdd(&gnsum2[32 + bch * 8 + nt], ssq);
  }
}

// ---------------- attention per 4x4 window ----------------
__global__ __launch_bounds__(128) void k_attn(const ushort_t* __restrict__ qkvb,
    ushort_t* __restrict__ ao) {
  __shared__ float ks[4224], vs[4224];   // [8h][16tok][33]
  const int tid = threadIdx.x;
  const int wid = blockIdx.x;
  const int b = wid >> 10, rem = wid & 1023, wh = rem >> 5, wc = rem & 31;
  const int tbase = (b << 14) + wh * 512 + wc * 4;
#pragma unroll 4
  for (int it = 0; it < 16; ++it) {
    const int i = it * 128 + tid;
    const int j = i >> 7, q = i & 127;
    const int which = q >> 6, hh2 = (q >> 3) & 7, d4 = (q & 7) << 2;
    const int tj = tbase + ((j >> 2) << 7) + (j & 3);
    us4 v = *(const us4*)(qkvb + (size_t)tj * 768 + 256 + which * 256 + hh2 * 32 + d4);
    float* dst = (which ? vs : ks) + (hh2 * 16 + j) * 33 + d4;
    dst[0] = b2f(v[0]); dst[1] = b2f(v[1]); dst[2] = b2f(v[2]); dst[3] = b2f(v[3]);
  }
  const int hh = tid >> 4, qi = tid & 15;
  const int tq = tbase + ((qi >> 2) << 7) + (qi & 3);
  float qv[32];
  {
    const ushort_t* qp = qkvb + (size_t)tq * 768 + hh * 32;
#pragma unroll
    for (int uq = 0; uq < 8; ++uq) {
      us4 v = *(const us4*)(qp + uq * 4);
#pragma unroll
      for (int e = 0; e < 4; ++e) qv[uq * 4 + e] = b2f(v[e]);
    }
  }
  __syncthreads();
  float sc[16];
#pragma unroll
  for (int j = 0; j < 16; ++j) {
    const float* kr = ks + (hh * 16 + j) * 33;
    float s = 0.f;
#pragma unroll
    for (int u2 = 0; u2 < 32; ++u2) s = fmaf(qv[u2], kr[u2], s);
    sc[j] = s * 0.17677669529663687f;
  }
  float m = sc[0];
#pragma unroll
  for (int j = 1; j < 16; ++j) m = fmaxf(m, sc[j]);
  float ssum = 0.f;
#pragma unroll
  for (int j = 0; j < 16; ++j) { sc[j] = __expf(sc[j] - m); ssum += sc[j]; }
  const float inv = 1.f / ssum;
  float oacc[32] = {};
#pragma unroll
  for (int j = 0; j < 16; ++j) {
    const float p = sc[j] * inv;
    const float* vr = vs + (hh * 16 + j) * 33;
#pragma unroll
    for (int u2 = 0; u2 < 32; ++u2) oacc[u2] = fmaf(p, vr[u2], oacc[u2]);
  }
  unsigned* dst = (unsigned*)(ao + (size_t)tq * 256 + hh * 32);
#pragma unroll
  for (int uq = 0; uq < 16; ++uq)
    dst[uq] = (unsigned)f2b(oacc[2 * uq]) | ((unsigned)f2b(oacc[2 * uq + 1]) << 16);
}

// ---------------- GN finalize ----------------
__global__ void k_gnfin(const float* __restrict__ sums, float* __restrict__ fin) {
  const int i = threadIdx.x;   // 0..31
  const float invN = 1.f / 524288.f;
  const float m = sums[i] * invN;
  const float var = sums[32 + i] * invN - m * m;
  fin[i] = m;
  fin[32 + i] = rsqrtf(fmaxf(var, 0.f) + EPSF);
}

// ---------------- GN1 apply: am bf16 -> amn bf16 ----------------
__global__ __launch_bounds__(256) void k_amn(const ushort_t* __restrict__ am,
    const float* __restrict__ fin, const float* __restrict__ gg,
    const float* __restrict__ gb, ushort_t* __restrict__ amn) {
  const size_t i = ((size_t)blockIdx.x * 256 + threadIdx.x) * 8;
  const int t = (int)(i >> 8), c = (int)(i & 255);
  const int b = t >> 14, grp = c >> 5;
  const float m = fin[b * 8 + grp], r = fin[32 + b * 8 + grp];
  us8 v = *(const us8*)(am + i);
  us8 o;
#pragma unroll
  for (int e = 0; e < 8; ++e)
    o[e] = f2b((b2f(v[e]) - m) * r * gg[c + e] + gb[c + e]);
  *(us8*)(amn + i) = o;
}

// ---------------- GN2 apply: u f32 -> hnext f32 ----------------
__global__ __launch_bounds__(256) void k_gnapply(const float* __restrict__ u,
    const float* __restrict__ fin2, const float* __restrict__ gg,
    const float* __restrict__ gb, float* __restrict__ hout) {
  const size_t base = ((size_t)blockIdx.x * 256 + threadIdx.x) * 4;
  const int b = (int)(base >> 22);
  const int ch = (int)((base >> 14) & 255);
  const int grp = ch >> 5;
  const float m = fin2[b * 8 + grp], r = fin2[32 + b * 8 + grp];
  const float gv = gg[ch], bv = gb[ch];
  float4 v = *(const float4*)(u + base);
  v.x = (v.x - m) * r * gv + bv;
  v.y = (v.y - m) * r * gv + bv;
  v.z = (v.z - m) * r * gv + bv;
  v.w = (v.w - m) * r * gv + bv;
  *(float4*)(hout + base) = v;
}

extern "C" void kernel_launch(void* const* d_in, const int* in_sizes, int n_in,
                              void* d_out, int out_size, void* d_ws, size_t ws_size,
                              hipStream_t stream) {
  const float* x      = (const float*)d_in[0];
  const float* h      = (const float*)d_in[1];
  const float* c      = (const float*)d_in[2];
  const float* ipw    = (const float*)d_in[3];
  const float* ipb    = (const float*)d_in[4];
  const float* lng    = (const float*)d_in[5];
  const float* lnb    = (const float*)d_in[6];
  const float* qkvw   = (const float*)d_in[7];
  const float* qkvb   = (const float*)d_in[8];
  const float* projw  = (const float*)d_in[9];
  const float* projb  = (const float*)d_in[10];
  const float* gatesw = (const float*)d_in[11];
  const float* gatesb = (const float*)d_in[12];
  const float* gng    = (const float*)d_in[13];
  const float* gnb    = (const float*)d_in[14];
  char* wsb  = (char*)d_ws;
  float* out = (float*)d_out;

  ushort_t* wip  = (ushort_t*)(wsb + O_WIP);
  ushort_t* wqkv = (ushort_t*)(wsb + O_WQKV);
  ushort_t* wprj = (ushort_t*)(wsb + O_WPRJ);
  ushort_t* wgat = (ushort_t*)(wsb + O_WGAT);
  float* gnsum   = (float*)(wsb + O_GN);
  float* gnfin   = (float*)(wsb + O_FIN);
  ushort_t* R2   = (ushort_t*)(wsb + O_R2);   // ao / amn
  ushort_t* R3   = (ushort_t*)(wsb + O_R3);   // xn / am
  ushort_t* R1   = (ushort_t*)(wsb + O_R1);   // comb / qkvbuf ; later u (f32)

  hipMemsetAsync(gnsum, 0, 512, stream);
  k_prep<<<2368, 256, 0, stream>>>(ipw, qkvw, projw, gatesw, wip, wqkv, wprj, wgat);
  k_comb<<<2560, 256, 0, stream>>>(x, h, R1);
  k_inproj_ln<<<1024, 256, 0, stream>>>(R1, wip, ipb, lng, lnb, R3);
  k_qkv<<<3072, 256, 0, stream>>>(R3, wqkv, qkvb, R1);
  k_attn<<<4096, 128, 0, stream>>>(R1, R2);
  k_proj<<<1024, 256, 0, stream>>>(R2, wprj, projb, R3, gnsum);
  k_gnfin<<<1, 32, 0, stream>>>(gnsum, gnfin);
  k_amn<<<8192, 256, 0, stream>>>(R3, gnfin, gng, gnb, R2);
  k_gates<<<4096, 256, 0, stream>>>(R2, wgat, gatesb, c, out + 16777216, (float*)R1,
                                    gnsum + 64);
  k_gnfin<<<1, 32, 0, stream>>>(gnsum + 64, gnfin + 64);
  k_gnapply<<<16384, 256, 0, stream>>>((float*)R1, gnfin + 64, gng, gnb, out);
}

// Round 4
// 749.009 us; speedup vs baseline: 1.7215x; 1.0541x over previous
//
#include <hip/hip_runtime.h>

#define DI __device__ __forceinline__

typedef unsigned short ushort_t;
typedef __attribute__((ext_vector_type(8))) short bf16x8;
typedef __attribute__((ext_vector_type(4))) float f32x4;
typedef __attribute__((ext_vector_type(4))) unsigned short us4;
typedef __attribute__((ext_vector_type(8))) unsigned short us8;

constexpr float EPSF = 1e-5f;

// ---- workspace byte offsets ----
constexpr size_t O_WIP  = 0;                       // 256x320 bf16
constexpr size_t O_WQKV = 163840;                  // 768x256 bf16
constexpr size_t O_WPRJ = 557056;                  // 256x256 bf16
constexpr size_t O_WGAT = 688128;                  // 1024x256 bf16
constexpr size_t O_GN   = 1736704;                 // 128 f32 (gn1 s,s2 | gn2 s,s2)
constexpr size_t O_FIN  = 1737216;                 // 128 f32
constexpr size_t O_R2   = 1740800;                 // 32MB: ao / amn
constexpr size_t O_R3   = O_R2 + 33554432;         // 32MB: xn / am
constexpr size_t O_R1   = O_R3 + 33554432;         // 96MB: comb / qkvbuf / u(f32)

DI ushort_t f2b(float f) {
  unsigned u = __float_as_uint(f);
  u += 0x7fff + ((u >> 16) & 1);          // round-nearest-even
  return (ushort_t)(u >> 16);
}
DI float b2f(ushort_t s) { return __uint_as_float(((unsigned)s) << 16); }

DI float fsig(float x) { return 1.f / (1.f + __expf(-x)); }
DI float ftanh(float x) {
  const float e = __expf(-2.f * fabsf(x));
  const float t = (1.f - e) / (1.f + e);
  return copysignf(t, x);
}

DI void cp16(ushort_t* lds, const ushort_t* g) {
  __builtin_amdgcn_global_load_lds(
      (const __attribute__((address_space(1))) unsigned*)g,
      (__attribute__((address_space(3))) unsigned*)lds, 16, 0, 0);
}

template<int N> DI void vm_wait() {
  if constexpr (N == 0)      asm volatile("s_waitcnt vmcnt(0)" ::: "memory");
  else if constexpr (N == 4) asm volatile("s_waitcnt vmcnt(4)" ::: "memory");
  else if constexpr (N == 5) asm volatile("s_waitcnt vmcnt(5)" ::: "memory");
}
DI void sbar() { __builtin_amdgcn_s_barrier(); }
DI void sb0()  { __builtin_amdgcn_sched_barrier(0); }

// ---------------- weight convert (layout preserved [o][k]) ----------------
__global__ __launch_bounds__(256) void k_prep(const float* __restrict__ ipw,
    const float* __restrict__ qkvw, const float* __restrict__ projw,
    const float* __restrict__ gatesw, ushort_t* __restrict__ d0,
    ushort_t* __restrict__ d1, ushort_t* __restrict__ d2, ushort_t* __restrict__ d3) {
  int i = blockIdx.x * 256 + threadIdx.x;
  if (i < 81920)  { d0[i] = f2b(ipw[i]);    return; }
  i -= 81920;
  if (i < 196608) { d1[i] = f2b(qkvw[i]);   return; }
  i -= 196608;
  if (i < 65536)  { d2[i] = f2b(projw[i]);  return; }
  i -= 65536;
  if (i < 262144) { d3[i] = f2b(gatesw[i]); return; }
}

// ---------------- transpose x,h (channel-major) -> comb bf16 [t][320] ----------------
__global__ __launch_bounds__(256) void k_comb(const float* __restrict__ x,
    const float* __restrict__ h, ushort_t* __restrict__ comb) {
  __shared__ float tile[32][257];
  const int tid = threadIdx.x;
  const int wid = blockIdx.x;
  const int b = wid / 640, r = wid % 640, ct = r / 64, pt = r % 64;
  const int p0 = pt * 256;
#pragma unroll 8
  for (int i = 0; i < 32; ++i) {
    const int cg = ct * 32 + i;
    const float* src = (cg < 64) ? x + (((size_t)(b * 64 + cg)) << 14)
                                 : h + (((size_t)(b * 256 + (cg - 64))) << 14);
    tile[i][tid] = src[p0 + tid];
  }
  __syncthreads();
  const int c = tid & 31;
#pragma unroll 8
  for (int i2 = 0; i2 < 32; ++i2) {
    const int tl = (tid >> 5) + i2 * 8;
    comb[(size_t)((b << 14) + p0 + tl) * 320 + ct * 32 + c] = f2b(tile[c][tl]);
  }
}

// ------- MFMA GEMM core: BM=128 BN=128 BK=32, 256thr, 3-buf counted-vmcnt pipeline -------
template<int K, int KT, bool GATESB>
DI void gemm_main(const ushort_t* __restrict__ A, const ushort_t* __restrict__ B,
                  int t0, int nb, ushort_t* smem, f32x4 acc[4][4]) {
  const int tid = threadIdx.x;
  const int lane = tid & 63, wave = tid >> 6;
  const int w2 = wave * 2;
  const int wm = wave >> 1, wn = wave & 1;
  const int kfs = lane >> 4, cc = lane & 15;
  const int aoff = kfs * 1024 + (wm * 64 + cc) * 8;
  const int boff = 4096 + kfs * 1024 + (wn * 64 + cc) * 8;

  auto stage = [&](int buf, int k0) {
#pragma unroll
    for (int i = 0; i < 2; ++i) {
      const int w2i = w2 + i;
      const int kslot = w2i >> 1;
      const int mrow = ((w2i & 1) << 6) + lane;
      const ushort_t* ga = A + (size_t)(t0 + mrow) * K + k0 + kslot * 8;
      cp16(smem + buf * 8192 + w2i * 512, ga);
      int ng;
      if (GATESB) ng = ((mrow >> 4) & 3) * 256 + nb + ((mrow >> 6) << 4) + (mrow & 15);
      else        ng = nb + mrow;
      const ushort_t* gb = B + (size_t)ng * K + k0 + kslot * 8;
      cp16(smem + buf * 8192 + 4096 + w2i * 512, gb);
    }
  };

  stage(0, 0);
  stage(1, 32);
  vm_wait<4>(); sbar(); sb0();
#pragma unroll
  for (int kt = 0; kt < KT; ++kt) {
    const int cur = (kt % 3) * 8192;
    if (kt + 2 < KT) stage((kt + 2) % 3, (kt + 2) * 32);
    bf16x8 a0 = *(const bf16x8*)(smem + cur + aoff);
    bf16x8 a1 = *(const bf16x8*)(smem + cur + aoff + 128);
    bf16x8 a2 = *(const bf16x8*)(smem + cur + aoff + 256);
    bf16x8 a3 = *(const bf16x8*)(smem + cur + aoff + 384);
    bf16x8 b0 = *(const bf16x8*)(smem + cur + boff);
    bf16x8 b1 = *(const bf16x8*)(smem + cur + boff + 128);
    bf16x8 b2 = *(const bf16x8*)(smem + cur + boff + 256);
    bf16x8 b3 = *(const bf16x8*)(smem + cur + boff + 384);
    acc[0][0] = __builtin_amdgcn_mfma_f32_16x16x32_bf16(a0, b0, acc[0][0], 0, 0, 0);
    acc[0][1] = __builtin_amdgcn_mfma_f32_16x16x32_bf16(a0, b1, acc[0][1], 0, 0, 0);
    acc[0][2] = __builtin_amdgcn_mfma_f32_16x16x32_bf16(a0, b2, acc[0][2], 0, 0, 0);
    acc[0][3] = __builtin_amdgcn_mfma_f32_16x16x32_bf16(a0, b3, acc[0][3], 0, 0, 0);
    acc[1][0] = __builtin_amdgcn_mfma_f32_16x16x32_bf16(a1, b0, acc[1][0], 0, 0, 0);
    acc[1][1] = __builtin_amdgcn_mfma_f32_16x16x32_bf16(a1, b1, acc[1][1], 0, 0, 0);
    acc[1][2] = __builtin_amdgcn_mfma_f32_16x16x32_bf16(a1, b2, acc[1][2], 0, 0, 0);
    acc[1][3] = __builtin_amdgcn_mfma_f32_16x16x32_bf16(a1, b3, acc[1][3], 0, 0, 0);
    acc[2][0] = __builtin_amdgcn_mfma_f32_16x16x32_bf16(a2, b0, acc[2][0], 0, 0, 0);
    acc[2][1] = __builtin_amdgcn_mfma_f32_16x16x32_bf16(a2, b1, acc[2][1], 0, 0, 0);
    acc[2][2] = __builtin_amdgcn_mfma_f32_16x16x32_bf16(a2, b2, acc[2][2], 0, 0, 0);
    acc[2][3] = __builtin_amdgcn_mfma_f32_16x16x32_bf16(a2, b3, acc[2][3], 0, 0, 0);
    acc[3][0] = __builtin_amdgcn_mfma_f32_16x16x32_bf16(a3, b0, acc[3][0], 0, 0, 0);
    acc[3][1] = __builtin_amdgcn_mfma_f32_16x16x32_bf16(a3, b1, acc[3][1], 0, 0, 0);
    acc[3][2] = __builtin_amdgcn_mfma_f32_16x16x32_bf16(a3, b2, acc[3][2], 0, 0, 0);
    acc[3][3] = __builtin_amdgcn_mfma_f32_16x16x32_bf16(a3, b3, acc[3][3], 0, 0, 0);
    if (kt + 1 < KT) {
      if (kt + 2 < KT) vm_wait<4>(); else vm_wait<0>();
      sbar(); sb0();
    }
  }
}

template<int NTOT>
DI void epi_store(f32x4 acc[4][4], ushort_t* __restrict__ C, const float* __restrict__ bias,
                  int t0, int n0g) {
  const int tid = threadIdx.x, lane = tid & 63, wave = tid >> 6;
  const int wm = wave >> 1, wn = wave & 1;
  const int r0 = (lane >> 4) * 4, cc = lane & 15;
#pragma unroll
  for (int fn = 0; fn < 4; ++fn) {
    const int n = wn * 64 + fn * 16 + cc;
    const float bv = bias[n0g + n];
#pragma unroll
    for (int fm = 0; fm < 4; ++fm) {
#pragma unroll
      for (int r = 0; r < 4; ++r) {
        const int m = wm * 64 + fm * 16 + r0 + r;
        C[(size_t)(t0 + m) * NTOT + n0g + n] = f2b(acc[fm][fn][r] + bv);
      }
    }
  }
}

// ---------------- in_proj + LayerNorm fused: BM=64 BN=256, 3-buf pipeline ----------------
__global__ __launch_bounds__(256) void k_inproj_ln(const ushort_t* __restrict__ A,
    const ushort_t* __restrict__ B, const float* __restrict__ bias,
    const float* __restrict__ lg, const float* __restrict__ lb, ushort_t* __restrict__ xn) {
  __shared__ ushort_t smem[30720];   // 3 x (A 2048 + B 8192) ushorts
  __shared__ float red[4][2][64];
  __shared__ float fin[2][64];
  const int tid = threadIdx.x, lane = tid & 63, wave = tid >> 6;
  const int t0 = blockIdx.x * 64;
  const int kfs = lane >> 4, cc = lane & 15;
  const int r0 = kfs * 4;
  const int aoff = kfs * 512 + cc * 8;
  const int boff = 2048 + kfs * 2048 + (wave * 64 + cc) * 8;

  auto stage = [&](int buf, int k0) {
#pragma unroll
    for (int rr = 0; rr < 5; ++rr) {
      const int r = wave * 5 + rr;
      const int e = r * 64 + lane;
      const ushort_t* src;
      if (r < 4) src = A + (size_t)(t0 + (e & 63)) * 320 + k0 + (e >> 6) * 8;
      else { const int e2 = e - 256; src = B + (size_t)(e2 & 255) * 320 + k0 + (e2 >> 8) * 8; }
      cp16(smem + buf * 10240 + r * 512, src);
    }
  };

  stage(0, 0);
  stage(1, 32);
  f32x4 acc[4][4] = {};
  vm_wait<5>(); sbar(); sb0();
#pragma unroll
  for (int kt = 0; kt < 10; ++kt) {
    const int cur = (kt % 3) * 10240;
    if (kt + 2 < 10) stage((kt + 2) % 3, (kt + 2) * 32);
    bf16x8 av[4], bv[4];
#pragma unroll
    for (int i = 0; i < 4; ++i) av[i] = *(const bf16x8*)(smem + cur + aoff + i * 128);
#pragma unroll
    for (int j = 0; j < 4; ++j) bv[j] = *(const bf16x8*)(smem + cur + boff + j * 128);
#pragma unroll
    for (int i = 0; i < 4; ++i)
#pragma unroll
      for (int j = 0; j < 4; ++j)
        acc[i][j] = __builtin_amdgcn_mfma_f32_16x16x32_bf16(av[i], bv[j], acc[i][j], 0, 0, 0);
    if (kt + 1 < 10) {
      if (kt + 2 < 10) vm_wait<5>(); else vm_wait<0>();
      sbar(); sb0();
    }
  }
  // bias add
  float bcol[4];
#pragma unroll
  for (int j = 0; j < 4; ++j) bcol[j] = bias[wave * 64 + j * 16 + cc];
#pragma unroll
  for (int i = 0; i < 4; ++i)
#pragma unroll
    for (int j = 0; j < 4; ++j)
#pragma unroll
      for (int r = 0; r < 4; ++r) acc[i][j][r] += bcol[j];
  // per-row partial sums over this wave's 64 cols
#pragma unroll
  for (int i = 0; i < 4; ++i) {
#pragma unroll
    for (int r = 0; r < 4; ++r) {
      float s  = acc[i][0][r] + acc[i][1][r] + acc[i][2][r] + acc[i][3][r];
      float s2 = acc[i][0][r] * acc[i][0][r] + acc[i][1][r] * acc[i][1][r]
               + acc[i][2][r] * acc[i][2][r] + acc[i][3][r] * acc[i][3][r];
#pragma unroll
      for (int m = 1; m < 16; m <<= 1) { s += __shfl_xor(s, m); s2 += __shfl_xor(s2, m); }
      if (cc == 0) { red[wave][0][i * 16 + r0 + r] = s; red[wave][1][i * 16 + r0 + r] = s2; }
    }
  }
  __syncthreads();
  if (tid < 64) {
    const float s  = red[0][0][tid] + red[1][0][tid] + red[2][0][tid] + red[3][0][tid];
    const float s2 = red[0][1][tid] + red[1][1][tid] + red[2][1][tid] + red[3][1][tid];
    const float m = s * (1.f / 256.f);
    const float var = s2 * (1.f / 256.f) - m * m;
    fin[0][tid] = m;
    fin[1][tid] = rsqrtf(fmaxf(var, 0.f) + EPSF);
  }
  __syncthreads();
  float lgv[4], lbv[4];
#pragma unroll
  for (int j = 0; j < 4; ++j) {
    const int n = wave * 64 + j * 16 + cc;
    lgv[j] = lg[n]; lbv[j] = lb[n];
  }
#pragma unroll
  for (int i = 0; i < 4; ++i)
#pragma unroll
    for (int r = 0; r < 4; ++r) {
      const int m = i * 16 + r0 + r;
      const float mu = fin[0][m], rs = fin[1][m];
      ushort_t* dst = xn + (size_t)(t0 + m) * 256 + wave * 64 + cc;
#pragma unroll
      for (int j = 0; j < 4; ++j)
        dst[j * 16] = f2b((acc[i][j][r] - mu) * rs * lgv[j] + lbv[j]);
    }
}

__global__ __launch_bounds__(256) void k_qkv(const ushort_t* __restrict__ A,
    const ushort_t* __restrict__ B, const float* __restrict__ bias, ushort_t* __restrict__ C) {
  __shared__ ushort_t smem[24576];
  const int wid = blockIdx.x, g = wid & 7, s = wid >> 3;
  const int mt = g * 64 + s / 6, nt = s % 6;
  f32x4 acc[4][4] = {};
  gemm_main<256, 8, false>(A, B, mt * 128, nt * 128, smem, acc);
  epi_store<768>(acc, C, bias, mt * 128, nt * 128);
}

// proj: store + GN1 partial sums
__global__ __launch_bounds__(256) void k_proj(const ushort_t* __restrict__ A,
    const ushort_t* __restrict__ B, const float* __restrict__ bias, ushort_t* __restrict__ C,
    float* __restrict__ gnsum) {
  __shared__ ushort_t smem[24576];
  const int wid = blockIdx.x, g = wid & 7, s = wid >> 3;
  const int mt = g * 64 + s / 2, nt = s % 2;
  const int t0 = mt * 128, n0g = nt * 128;
  f32x4 acc[4][4] = {};
  gemm_main<256, 8, false>(A, B, t0, n0g, smem, acc);
  const int tid = threadIdx.x, lane = tid & 63, wave = tid >> 6;
  const int wm = wave >> 1, wn = wave & 1;
  const int r0 = (lane >> 4) * 4, cc = lane & 15;
  float sA = 0.f, s2A = 0.f, sB = 0.f, s2B = 0.f;
#pragma unroll
  for (int fn = 0; fn < 4; ++fn) {
    const int n = wn * 64 + fn * 16 + cc;
    const float bv = bias[n0g + n];
#pragma unroll
    for (int fm = 0; fm < 4; ++fm) {
#pragma unroll
      for (int r = 0; r < 4; ++r) {
        const int m = wm * 64 + fm * 16 + r0 + r;
        const float v = acc[fm][fn][r] + bv;
        C[(size_t)(t0 + m) * 256 + n0g + n] = f2b(v);
        if (fn < 2) { sA += v; s2A += v * v; } else { sB += v; s2B += v * v; }
      }
    }
  }
#pragma unroll
  for (int o = 32; o; o >>= 1) {
    sA += __shfl_down(sA, o); s2A += __shfl_down(s2A, o);
    sB += __shfl_down(sB, o); s2B += __shfl_down(s2B, o);
  }
  if (lane == 0) {
    const int bch = t0 >> 14;
    const int gb0 = (n0g >> 5) + wn * 2;
    atomicAdd(&gnsum[bch * 8 + gb0], sA);      atomicAdd(&gnsum[32 + bch * 8 + gb0], s2A);
    atomicAdd(&gnsum[bch * 8 + gb0 + 1], sB);  atomicAdd(&gnsum[32 + bch * 8 + gb0 + 1], s2B);
  }
}

// gates: GEMM + LSTM elementwise in MFMA layout (gate = fn via B-row remap)
__global__ __launch_bounds__(256) void k_gates(const ushort_t* __restrict__ A,
    const ushort_t* __restrict__ B, const float* __restrict__ gbias,
    const float* __restrict__ cin, float* __restrict__ cnext, float* __restrict__ u,
    float* __restrict__ gnsum2) {
  __shared__ ushort_t smem[24576];
  const int wid = blockIdx.x, g = wid & 7, s = wid >> 3;
  const int mt = g * 64 + (s >> 3), nt = s & 7;
  const int t0 = mt * 128, ch0 = nt * 32;
  f32x4 acc[4][4] = {};
  gemm_main<256, 8, true>(A, B, t0, ch0, smem, acc);

  const int tid = threadIdx.x, lane = tid & 63, wave = tid >> 6;
  const int wm = wave >> 1, wn = wave & 1;
  const int r0 = (lane >> 4) * 4, cc = lane & 15;
  const int bch = t0 >> 14, pix0 = t0 & 16383;
  const int ch = ch0 + wn * 16 + cc;
  const float bi = gbias[ch], bf_ = gbias[256 + ch];
  const float bo = gbias[512 + ch], bg = gbias[768 + ch];
  const size_t chbase = ((size_t)(bch * 256 + ch)) << 14;
  float ssum = 0.f, ssq = 0.f;
#pragma unroll
  for (int fm = 0; fm < 4; ++fm) {
    const int pix = pix0 + wm * 64 + fm * 16 + r0;
    const float4 cv = *(const float4*)(cin + chbase + pix);
    float cn[4], uv[4];
#pragma unroll
    for (int r = 0; r < 4; ++r) {
      const float iv = fsig(acc[fm][0][r] + bi);
      const float fv = fsig(acc[fm][1][r] + bf_);
      const float ov = fsig(acc[fm][2][r] + bo);
      const float gv = ftanh(acc[fm][3][r] + bg);
      const float cold = (&cv.x)[r];
      const float c2 = fv * cold + iv * gv;
      cn[r] = c2;
      const float uu = ov * ftanh(c2);
      uv[r] = uu; ssum += uu; ssq += uu * uu;
    }
    *(float4*)(cnext + chbase + pix) = *(float4*)cn;
    *(float4*)(u + chbase + pix)     = *(float4*)uv;
  }
#pragma unroll
  for (int o = 32; o; o >>= 1) { ssum += __shfl_down(ssum, o); ssq += __shfl_down(ssq, o); }
  if (lane == 0) {
    atomicAdd(&gnsum2[bch * 8 + nt], ssum);
    atomicAdd(&gnsum2[32 + bch * 8 + nt], ssq);
  }
}

// ---------------- attention per 4x4 window (conflict-free float4 LDS) ----------------
__global__ __launch_bounds__(128) void k_attn(const ushort_t* __restrict__ qkvb,
    ushort_t* __restrict__ ao) {
  __shared__ float ks[4128], vs[4128];   // per-head base h*516, row j*32
  const int tid = threadIdx.x;
  const int wid = blockIdx.x;
  const int b = wid >> 10, rem = wid & 1023, wh = rem >> 5, wc = rem & 31;
  const int tbase = (b << 14) + wh * 512 + wc * 4;
  {
    const int which = tid >> 6, hh2 = (tid >> 3) & 7, d4 = (tid & 7) << 2;
    float* base = (which ? vs : ks) + hh2 * 516 + d4;
    const ushort_t* gsrc = qkvb + 256 + which * 256 + hh2 * 32 + d4;
#pragma unroll
    for (int j = 0; j < 16; ++j) {
      const int tj = tbase + ((j >> 2) << 7) + (j & 3);
      us4 v = *(const us4*)(gsrc + (size_t)tj * 768);
      float* dst = base + j * 32;
      dst[0] = b2f(v[0]); dst[1] = b2f(v[1]); dst[2] = b2f(v[2]); dst[3] = b2f(v[3]);
    }
  }
  const int hh = tid >> 4, qi = tid & 15;
  const int tq = tbase + ((qi >> 2) << 7) + (qi & 3);
  float qv[32];
  {
    const ushort_t* qp = qkvb + (size_t)tq * 768 + hh * 32;
#pragma unroll
    for (int uq = 0; uq < 8; ++uq) {
      us4 v = *(const us4*)(qp + uq * 4);
#pragma unroll
      for (int e = 0; e < 4; ++e) qv[uq * 4 + e] = b2f(v[e]);
    }
  }
  __syncthreads();
  float sc[16];
#pragma unroll
  for (int j = 0; j < 16; ++j) {
    const float4* kr = (const float4*)(ks + hh * 516 + j * 32);
    float s = 0.f;
#pragma unroll
    for (int u2 = 0; u2 < 8; ++u2) {
      const float4 kk = kr[u2];
      s = fmaf(qv[u2 * 4], kk.x, s);
      s = fmaf(qv[u2 * 4 + 1], kk.y, s);
      s = fmaf(qv[u2 * 4 + 2], kk.z, s);
      s = fmaf(qv[u2 * 4 + 3], kk.w, s);
    }
    sc[j] = s * 0.17677669529663687f;
  }
  float m = sc[0];
#pragma unroll
  for (int j = 1; j < 16; ++j) m = fmaxf(m, sc[j]);
  float ssum = 0.f;
#pragma unroll
  for (int j = 0; j < 16; ++j) { sc[j] = __expf(sc[j] - m); ssum += sc[j]; }
  const float inv = 1.f / ssum;
  float4 oacc[8] = {};
#pragma unroll
  for (int j = 0; j < 16; ++j) {
    const float p = sc[j] * inv;
    const float4* vr = (const float4*)(vs + hh * 516 + j * 32);
#pragma unroll
    for (int u2 = 0; u2 < 8; ++u2) {
      const float4 vv = vr[u2];
      oacc[u2].x = fmaf(p, vv.x, oacc[u2].x);
      oacc[u2].y = fmaf(p, vv.y, oacc[u2].y);
      oacc[u2].z = fmaf(p, vv.z, oacc[u2].z);
      oacc[u2].w = fmaf(p, vv.w, oacc[u2].w);
    }
  }
  unsigned* dst = (unsigned*)(ao + (size_t)tq * 256 + hh * 32);
#pragma unroll
  for (int u2 = 0; u2 < 8; ++u2) {
    dst[u2 * 2]     = (unsigned)f2b(oacc[u2].x) | ((unsigned)f2b(oacc[u2].y) << 16);
    dst[u2 * 2 + 1] = (unsigned)f2b(oacc[u2].z) | ((unsigned)f2b(oacc[u2].w) << 16);
  }
}

// ---------------- GN finalize ----------------
__global__ void k_gnfin(const float* __restrict__ sums, float* __restrict__ fin) {
  const int i = threadIdx.x;   // 0..31
  const float invN = 1.f / 524288.f;
  const float m = sums[i] * invN;
  const float var = sums[32 + i] * invN - m * m;
  fin[i] = m;
  fin[32 + i] = rsqrtf(fmaxf(var, 0.f) + EPSF);
}

// ---------------- GN1 apply: am bf16 -> amn bf16 ----------------
__global__ __launch_bounds__(256) void k_amn(const ushort_t* __restrict__ am,
    const float* __restrict__ fin, const float* __restrict__ gg,
    const float* __restrict__ gb, ushort_t* __restrict__ amn) {
  const size_t i = ((size_t)blockIdx.x * 256 + threadIdx.x) * 8;
  const int t = (int)(i >> 8), c = (int)(i & 255);
  const int b = t >> 14, grp = c >> 5;
  const float m = fin[b * 8 + grp], r = fin[32 + b * 8 + grp];
  us8 v = *(const us8*)(am + i);
  us8 o;
#pragma unroll
  for (int e = 0; e < 8; ++e)
    o[e] = f2b((b2f(v[e]) - m) * r * gg[c + e] + gb[c + e]);
  *(us8*)(amn + i) = o;
}

// ---------------- GN2 apply: u f32 -> hnext f32 ----------------
__global__ __launch_bounds__(256) void k_gnapply(const float* __restrict__ u,
    const float* __restrict__ fin2, const float* __restrict__ gg,
    const float* __restrict__ gb, float* __restrict__ hout) {
  const size_t base = ((size_t)blockIdx.x * 256 + threadIdx.x) * 4;
  const int b = (int)(base >> 22);
  const int ch = (int)((base >> 14) & 255);
  const int grp = ch >> 5;
  const float m = fin2[b * 8 + grp], r = fin2[32 + b * 8 + grp];
  const float gv = gg[ch], bv = gb[ch];
  float4 v = *(const float4*)(u + base);
  v.x = (v.x - m) * r * gv + bv;
  v.y = (v.y - m) * r * gv + bv;
  v.z = (v.z - m) * r * gv + bv;
  v.w = (v.w - m) * r * gv + bv;
  *(float4*)(hout + base) = v;
}

extern "C" void kernel_launch(void* const* d_in, const int* in_sizes, int n_in,
                              void* d_out, int out_size, void* d_ws, size_t ws_size,
                              hipStream_t stream) {
  const float* x      = (const float*)d_in[0];
  const float* h      = (const float*)d_in[1];
  const float* c      = (const float*)d_in[2];
  const float* ipw    = (const float*)d_in[3];
  const float* ipb    = (const float*)d_in[4];
  const float* lng    = (const float*)d_in[5];
  const float* lnb    = (const float*)d_in[6];
  const float* qkvw   = (const float*)d_in[7];
  const float* qkvb   = (const float*)d_in[8];
  const float* projw  = (const float*)d_in[9];
  const float* projb  = (const float*)d_in[10];
  const float* gatesw = (const float*)d_in[11];
  const float* gatesb = (const float*)d_in[12];
  const float* gng    = (const float*)d_in[13];
  const float* gnb    = (const float*)d_in[14];
  char* wsb  = (char*)d_ws;
  float* out = (float*)d_out;

  ushort_t* wip  = (ushort_t*)(wsb + O_WIP);
  ushort_t* wqkv = (ushort_t*)(wsb + O_WQKV);
  ushort_t* wprj = (ushort_t*)(wsb + O_WPRJ);
  ushort_t* wgat = (ushort_t*)(wsb + O_WGAT);
  float* gnsum   = (float*)(wsb + O_GN);
  float* gnfin   = (float*)(wsb + O_FIN);
  ushort_t* R2   = (ushort_t*)(wsb + O_R2);   // ao / amn
  ushort_t* R3   = (ushort_t*)(wsb + O_R3);   // xn / am
  ushort_t* R1   = (ushort_t*)(wsb + O_R1);   // comb / qkvbuf ; later u (f32)

  hipMemsetAsync(gnsum, 0, 512, stream);
  k_prep<<<2368, 256, 0, stream>>>(ipw, qkvw, projw, gatesw, wip, wqkv, wprj, wgat);
  k_comb<<<2560, 256, 0, stream>>>(x, h, R1);
  k_inproj_ln<<<1024, 256, 0, stream>>>(R1, wip, ipb, lng, lnb, R3);
  k_qkv<<<3072, 256, 0, stream>>>(R3, wqkv, qkvb, R1);
  k_attn<<<4096, 128, 0, stream>>>(R1, R2);
  k_proj<<<1024, 256, 0, stream>>>(R2, wprj, projb, R3, gnsum);
  k_gnfin<<<1, 32, 0, stream>>>(gnsum, gnfin);
  k_amn<<<8192, 256, 0, stream>>>(R3, gnfin, gng, gnb, R2);
  k_gates<<<4096, 256, 0, stream>>>(R2, wgat, gatesb, c, out + 16777216, (float*)R1,
                                    gnsum + 64);
  k_gnfin<<<1, 32, 0, stream>>>(gnsum + 64, gnfin + 64);
  k_gnapply<<<16384, 256, 0, stream>>>((float*)R1, gnfin + 64, gng, gnb, out);
}